// Round 9
// baseline (225.017 us; speedup 1.0000x reference)
//
#include <hip/hip_runtime.h>
#include <math.h>

#define HID 256
#define CIN 288      // HID + POS
#define NTOK 16384   // B*N
#define NSEQ 2048
#define NH 4
#define DHD 64
#define TWO_PI 6.2831853071795864769f

typedef __attribute__((ext_vector_type(8))) short bf16x8;
typedef __attribute__((ext_vector_type(4))) float f32x4;
typedef __attribute__((ext_vector_type(4))) unsigned short u16x4;

__device__ __forceinline__ ushort f2bf(float x) {
    unsigned u = __float_as_uint(x);
    u = (u + 0x7FFFu + ((u >> 16) & 1u)) >> 16;
    return (ushort)u;
}

__device__ __forceinline__ float fast_exp2(float x) {
    return __builtin_amdgcn_exp2f(x);   // v_exp_f32
}

// pack two fp32 -> one dword of truncated bf16 (lo=a, hi=b) via v_perm_b32
__device__ __forceinline__ unsigned pack_bf_trunc(float a, float b) {
    return __builtin_amdgcn_perm(__float_as_uint(b), __float_as_uint(a), 0x07060302u);
}

// async global->LDS, 16 B per lane: LDS dst = base + lane*16 (wave-uniform base)
__device__ __forceinline__ void gload_lds16(const ushort* g, ushort* l) {
    __builtin_amdgcn_global_load_lds(
        (const __attribute__((address_space(1))) unsigned*)g,
        (__attribute__((address_space(3))) unsigned*)l, 16, 0, 0);
}

// LDS chunk swizzle for 128B rows (8 x 16B chunks/row): uniform bank classes
__device__ __forceinline__ int sw(int row) {
    return (((row >> 3) << 1) ^ row) & 7;
}

// chunk swizzle for 64B rows (4 x 16B chunks/row)
__device__ __forceinline__ int swv(int row) {
    return ((row & 3) ^ ((row >> 2) & 3));
}

// ---------------------------------------------------------------------------
// Kernel 1 (MERGED PREP): pos_mlp(8-thr/token) | cast_wo | fuse_w | cast_x.
// Unchanged from round 8 (VGPR 76, no spill). Warm-up dispatches are ~50us
// (L3-cold); steady state lower.
// ---------------------------------------------------------------------------
__global__ __launch_bounds__(256) void prep_kernel(
        const float* __restrict__ icoords, const float* __restrict__ qcoords,
        const float* __restrict__ w1, const float* __restrict__ b1,
        const float* __restrict__ w2, const float* __restrict__ b2,
        const float* __restrict__ X, const float* __restrict__ Qin,
        const float* __restrict__ inW,
        const float* __restrict__ Wq, const float* __restrict__ Wk,
        const float* __restrict__ Wv,
        const float* __restrict__ Wo,
        ushort* __restrict__ ip, ushort* __restrict__ qp,
        ushort* __restrict__ Wb, ushort* __restrict__ WoB) {
    __shared__ float SMEM[4160];
    const int blk = blockIdx.x;
    const int t = threadIdx.x;

    if (blk < 1024) {
        // ---------------- pos_mlp (8 threads per token) ----------------
        float* sw1t = SMEM;            // [96][32] transposed
        float* sb1  = SMEM + 3072;     // [32]
        float* sw2  = SMEM + 3104;     // [32][32]
        float* sb2  = SMEM + 4128;     // [32]
        for (int i = t; i < 96 * 32; i += 256) {
            const int e = i >> 5, r = i & 31;
            sw1t[i] = w1[r * 96 + e];
        }
        for (int i = t; i < 32 * 32; i += 256) sw2[i] = w2[i];
        if (t < 32) { sb1[t] = b1[t]; sb2[t] = b2[t]; }
        __syncthreads();

        const int p = t & 7;                       // owns h rows 4p..4p+3
        const int tok = blk * 32 + (t >> 3);
        const int which = tok >> 14;
        const int m = tok & (NTOK - 1);
        const float* cr = (which ? qcoords : icoords) + m * 4;
        const float x = cr[1] * TWO_PI;
        const float y = cr[2] * TWO_PI;
        const float z = cr[3] * TWO_PI;

        f32x4 h = *(const f32x4*)&sb1[4 * p];

        for (int jj = 0; jj < 16; ++jj) {
            const float inv = 1.0f / (1.0f + 0.0625f * (float)jj);
            const float xs = x * inv, ys = y * inv, zs = z * inv;
            const float cx = __cosf(xs);
            float vals[6];
            int idx[6];
            vals[0] = __sinf(ys);  idx[0] = 2 * jj;
            vals[1] = __cosf(ys);  idx[1] = 2 * jj + 1;
            vals[2] = __sinf(xs);  idx[2] = 32 + 2 * jj;
            vals[3] = cx;          idx[3] = 32 + 2 * jj + 1;
            vals[4] = __sinf(zs);  idx[4] = 64 + 2 * jj;
            vals[5] = cx;          idx[5] = 64 + 2 * jj + 1;   // reference bug: cos of x
#pragma unroll
            for (int u = 0; u < 6; ++u)
                h += vals[u] * *(const f32x4*)&sw1t[idx[u] * 32 + 4 * p];
        }
#pragma unroll
        for (int j = 0; j < 4; ++j) h[j] = fmaxf(h[j], 0.f);

        float part[32];
#pragma unroll
        for (int c = 0; c < 32; ++c) {
            const f32x4 w4 = *(const f32x4*)&sw2[c * 32 + 4 * p];
            part[c] = (h[0] * w4[0] + h[1] * w4[1]) + (h[2] * w4[2] + h[3] * w4[3]);
        }
#pragma unroll
        for (int c = 0; c < 32; ++c) part[c] += __shfl_xor(part[c], 1);
#pragma unroll
        for (int c = 0; c < 32; ++c) part[c] += __shfl_xor(part[c], 2);
#pragma unroll
        for (int c = 0; c < 32; ++c) part[c] += __shfl_xor(part[c], 4);

        ushort* dst = (which ? qp : ip) + (size_t)m * CIN + 256;
        u16x4 w;
#pragma unroll
        for (int r = 0; r < 4; ++r) w[r] = f2bf(sb2[4 * p + r] + part[4 * p + r]);
        *(u16x4*)(dst + 4 * p) = w;
    } else if (blk < 1088) {
        // ---------------- cast_wo ----------------
        const int f = ((blk - 1024) * 256 + t) * 4;
        const float4 a = *(const float4*)(Wo + f);
        u16x4 o = {f2bf(a.x), f2bf(a.y), f2bf(a.z), f2bf(a.w)};
        *(u16x4*)(WoB + f) = o;
    } else if (blk < 1856) {
        // ---------------- fuse_w ----------------
        float* wrow = SMEM;
        const int idx = blk - 1088;
        const int o = idx & 255;
        const int mat = idx >> 8;
        wrow[t] = inW[(mat * 256 + o) * 256 + t];
        __syncthreads();
        const float* Wm = (mat == 0) ? Wq : ((mat == 1) ? Wk : Wv);
        const int t2 = 256 + (t & 31);
        float acc0 = 0.f, acc1 = 0.f;
#pragma unroll 4
        for (int h = 0; h < 256; ++h) {
            const float wh = wrow[h];
            acc0 += wh * Wm[h * CIN + t];
            acc1 += wh * Wm[h * CIN + t2];
        }
        ushort* dst = Wb + (size_t)(mat * 256 + o) * CIN;
        dst[t] = f2bf(acc0);
        if (t < 32) dst[t2] = f2bf(acc1);
    } else {
        // ---------------- cast_x ----------------
        const int i = blk - 1856;
        const int which = i >> 11;
        const size_t f = ((size_t)(i & 2047) * 256 + t) * 8;
        const int row = (int)(f >> 8);
        const int col = (int)(f & 255);
        const float* src = which ? Qin : X;
        ushort* dst = which ? qp : ip;
        const float4 a = *(const float4*)(src + f);
        const float4 b = *(const float4*)(src + f + 4);
        u16x4 o0 = {f2bf(a.x), f2bf(a.y), f2bf(a.z), f2bf(a.w)};
        u16x4 o1 = {f2bf(b.x), f2bf(b.y), f2bf(b.z), f2bf(b.w)};
        *(u16x4*)(dst + (size_t)row * CIN + col) = o0;
        *(u16x4*)(dst + (size_t)row * CIN + col + 4) = o1;
    }
}

// ---------------------------------------------------------------------------
// Kernel 2: QKV projection -- COUNTED-VMCNT PIPELINE (attn's proven scheme).
// Previous version's __syncthreads per k-step drained vmcnt(0) INCLUDING the
// prefetch issued just above it -> zero overlap, 9 serial ~500cyc drains per
// block. Now: 3 buffers x (A 8KB + B 4KB) = 36KB; B-tile staged via
// gload_lds too, so ALL loop VMEM is gload_lds (3 loads/thread/tile) and the
// counted wait is exact: vmcnt(3) leaves tile t+1 in flight across the
// barrier; vmcnt(0) only at the last tile. XOR chunk swizzle
// (chunk ^= (row>>1)&3) on A and B makes the fragment ds_read_b128s 2-way
// (free) instead of the previous 8-way (2.9x, m136). Data identical ->
// results bit-identical.
// ---------------------------------------------------------------------------
__global__ __launch_bounds__(256) void qkv_mfma(
        const ushort* __restrict__ qp, const ushort* __restrict__ ip,
        const ushort* __restrict__ Wb, const float* __restrict__ bias,
        ushort* __restrict__ qout, ushort* __restrict__ kout, ushort* __restrict__ vout) {
    __shared__ ushort SA[3 * 6144];   // 3 x (A 8KB + B 4KB) = 36 KB
    const int wv = threadIdx.x >> 6, lane = threadIdx.x & 63;
    const int l16 = lane & 15, quad = lane >> 4;
    const int m0b = blockIdx.x * 128;
    const int y = blockIdx.y;
    const int mat = y >> 2;
    const int n0 = y * 64;
    const ushort* A = (mat == 0) ? qp : ip;

    // A staging: 512 chunks (128 rows x 4 chunks of 16B); this thread does
    // chunks wv*128 + i*64 + lane, i=0,1. Swizzle: cc ^= (row>>1)&3.
    size_t asrc[2];
    int adst[2];
#pragma unroll
    for (int i = 0; i < 2; ++i) {
        const int idx = wv * 128 + i * 64 + lane;
        const int row = idx >> 2;
        const int cc = (idx & 3) ^ ((row >> 1) & 3);
        asrc[i] = (size_t)(m0b + row) * CIN + cc * 8;
        adst[i] = (wv * 128 + i * 64) * 8;
    }
    // B staging: 256 chunks (64 rows x 4); this thread does chunk wv*64+lane.
    const int bidx = wv * 64 + lane;
    const int brow = bidx >> 2;
    const int bcc = (bidx & 3) ^ ((brow >> 1) & 3);
    const size_t bsrc = (size_t)(n0 + brow) * CIN + bcc * 8;
    const int bdst = 4096 + wv * 512;

    // fragment read offsets: swizzled chunk = quad ^ ((l16>>1)&3) (row>>1 &3
    // == (l16>>1)&3 for both A rows 32wv+16s+l16 and B rows 16c+l16).
    const int rsw = quad ^ ((l16 >> 1) & 3);
    int aoff[2];
#pragma unroll
    for (int s = 0; s < 2; ++s)
        aoff[s] = ((32 * wv + 16 * s + l16) * 4 + rsw) * 8;
    int boff[4];
#pragma unroll
    for (int c = 0; c < 4; ++c)
        boff[c] = 4096 + ((16 * c + l16) * 4 + rsw) * 8;

    f32x4 acc[2][4];
#pragma unroll
    for (int s = 0; s < 2; ++s)
#pragma unroll
        for (int c = 0; c < 4; ++c) acc[s][c] = (f32x4){0.f, 0.f, 0.f, 0.f};

    // prologue: stage tiles 0,1 (6 loads in flight)
#pragma unroll
    for (int pt = 0; pt < 2; ++pt) {
        ushort* db = SA + pt * 6144;
        gload_lds16(A + asrc[0] + pt * 32, db + adst[0]);
        gload_lds16(A + asrc[1] + pt * 32, db + adst[1]);
        gload_lds16(Wb + bsrc + pt * 32, db + bdst);
    }

    int co = 0, po = 12288;   // consumer / prefetch buffer offsets (ushorts)
    for (int t = 0; t < 9; ++t) {
        // retire OWN tile-t loads; tile t+1's 3 stay in flight across barrier
        if (t < 8) asm volatile("s_waitcnt vmcnt(3)" ::: "memory");
        else       asm volatile("s_waitcnt vmcnt(0)" ::: "memory");
        __builtin_amdgcn_s_barrier();

        if (t + 2 < 9) {   // prefetch tile t+2 into buf freed at t-1
            ushort* db = SA + po;
            gload_lds16(A + asrc[0] + (t + 2) * 32, db + adst[0]);
            gload_lds16(A + asrc[1] + (t + 2) * 32, db + adst[1]);
            gload_lds16(Wb + bsrc + (t + 2) * 32, db + bdst);
            po = (po == 12288) ? 0 : po + 6144;
        }
        const ushort* buf = SA + co;
        co = (co == 12288) ? 0 : co + 6144;

        bf16x8 af[2], bf[4];
#pragma unroll
        for (int s = 0; s < 2; ++s)
            af[s] = *(const bf16x8*)(buf + aoff[s]);
#pragma unroll
        for (int c = 0; c < 4; ++c)
            bf[c] = *(const bf16x8*)(buf + boff[c]);
        if (mat < 2) {
#pragma unroll
            for (int s = 0; s < 2; ++s)
#pragma unroll
                for (int c = 0; c < 4; ++c)
                    acc[s][c] = __builtin_amdgcn_mfma_f32_16x16x32_bf16(bf[c], af[s], acc[s][c], 0, 0, 0);
        } else {
#pragma unroll
            for (int s = 0; s < 2; ++s)
#pragma unroll
                for (int c = 0; c < 4; ++c)
                    acc[s][c] = __builtin_amdgcn_mfma_f32_16x16x32_bf16(af[s], bf[c], acc[s][c], 0, 0, 0);
        }
    }

    const int h = y & 3;
    const int m0 = m0b + wv * 32;
    if (mat < 2) {
        const float scale = (mat == 0) ? (0.125f * 1.44269504088896f) : 1.0f;
        ushort* out = (mat == 0) ? qout : kout;
#pragma unroll
        for (int s = 0; s < 2; ++s) {
            const int tokm = m0 + 16 * s + l16;
            const int b = tokm >> 11, nn = tokm & (NSEQ - 1);
#pragma unroll
            for (int c = 0; c < 4; ++c) {
                const f32x4 b4 = *(const f32x4*)&bias[n0 + 16 * c + quad * 4];
                u16x4 w;
#pragma unroll
                for (int r = 0; r < 4; ++r) w[r] = f2bf((acc[s][c][r] + b4[r]) * scale);
                *(u16x4*)(out + ((size_t)(b * NH + h) * NSEQ + nn) * DHD + 16 * c + quad * 4) = w;
            }
        }
    } else {
#pragma unroll
        for (int s = 0; s < 2; ++s) {
            const int tok0 = m0 + 16 * s + quad * 4;
            const int b = tok0 >> 11, nn0 = tok0 & (NSEQ - 1);
#pragma unroll
            for (int c = 0; c < 4; ++c) {
                const int d = 16 * c + l16;
                const float bv = bias[n0 + d];
                u16x4 w;
#pragma unroll
                for (int r = 0; r < 4; ++r) w[r] = f2bf(acc[s][c][r] + bv);
                *(u16x4*)(vout + ((size_t)(b * NH + h) * DHD + d) * NSEQ + nn0) = w;
            }
        }
    }
}

// ---------------------------------------------------------------------------
// Kernel 3: MFMA flash attention (unchanged from round 8).
// ---------------------------------------------------------------------------
__global__ __launch_bounds__(512, 4) void attn_kernel(
        const ushort* __restrict__ q, const ushort* __restrict__ k,
        const ushort* __restrict__ v, ushort* __restrict__ out) {
    __shared__ ushort SL[24576];   // 48 KB
    const int bh = blockIdx.y;
    const int wv = threadIdx.x >> 6;     // 0..7
    const int grp = wv >> 2;             // key half
    const int wq = wv & 3;               // q sub-block within group
    const int lane = threadIdx.x & 63;
    const int l16 = lane & 15, quad = lane >> 4;
    const int q0 = blockIdx.x * 128 + wq * 32;

    const ushort* qb = q + (size_t)bh * NSEQ * DHD;
    const ushort* kb = k + (size_t)bh * NSEQ * DHD + (size_t)(grp * 1024) * DHD;
    const ushort* vb = v + (size_t)bh * DHD * NSEQ + grp * 1024;
    ushort* SG = SL + grp * 12288;       // per-group staging base (ushorts)

    bf16x8 qf[2][2];
#pragma unroll
    for (int s = 0; s < 2; ++s)
#pragma unroll
        for (int hh = 0; hh < 2; ++hh)
            qf[s][hh] = *(const bf16x8*)(qb + (size_t)(q0 + 16 * s + l16) * DHD + 32 * hh + quad * 8);

    const int krow_s = 8 * wq + (lane >> 3);
    const int kcg = (lane & 7) ^ sw(krow_s);
    const size_t ksrc = (size_t)krow_s * DHD + kcg * 8;
    const int kdst = wq * 512;
    const int vrow_s = 16 * wq + (lane >> 2);
    const int vcg = (lane & 3) ^ swv(vrow_s);
    const size_t vsrc = (size_t)vrow_s * NSEQ + vcg * 8;
    const int vdst = wq * 512;

    const int krow = 8 * (l16 >> 2) + (l16 & 3);
    int koff[2][2];
    int voff[4];
#pragma unroll
    for (int m = 0; m < 2; ++m) {
        const int row = krow + 4 * m;
#pragma unroll
        for (int hh = 0; hh < 2; ++hh)
            koff[m][hh] = row * 64 + (((hh * 4 + quad) ^ sw(row))) * 8;
    }
#pragma unroll
    for (int c = 0; c < 4; ++c) {
        const int d = 16 * c + l16;
        voff[c] = 2048 + d * 32 + ((quad ^ swv(d))) * 8;
    }

    f32x4 Oc[2][4];
#pragma unroll
    for (int s = 0; s < 2; ++s)
#pragma unroll
        for (int c = 0; c < 4; ++c) Oc[s][c] = (f32x4){0.f, 0.f, 0.f, 0.f};
    float lr[2] = {0.f, 0.f};

#pragma unroll
    for (int pt = 0; pt < 2; ++pt) {
        ushort* db = SG + pt * 4096;
        gload_lds16(kb + (size_t)(pt * 32) * DHD + ksrc, db + kdst);
        gload_lds16(vb + pt * 32 + vsrc, db + 2048 + vdst);
    }

    int co = 0, po = 8192;
    for (int t = 0; t < 32; ++t) {
        if (t < 31) asm volatile("s_waitcnt vmcnt(2)" ::: "memory");
        else        asm volatile("s_waitcnt vmcnt(0)" ::: "memory");
        __builtin_amdgcn_s_barrier();

        if (t < 30) {
            ushort* db = SG + po;
            gload_lds16(kb + (size_t)((t + 2) * 32) * DHD + ksrc, db + kdst);
            gload_lds16(vb + (t + 2) * 32 + vsrc, db + 2048 + vdst);
            po = (po == 8192) ? 0 : po + 4096;
        }
        const ushort* buf = SG + co;
        co = (co == 8192) ? 0 : co + 4096;

        bf16x8 kf[2][2], vf[4];
#pragma unroll
        for (int m = 0; m < 2; ++m)
#pragma unroll
            for (int hh = 0; hh < 2; ++hh)
                kf[m][hh] = *(const bf16x8*)(buf + koff[m][hh]);
#pragma unroll
        for (int c = 0; c < 4; ++c)
            vf[c] = *(const bf16x8*)(buf + voff[c]);

#pragma unroll
        for (int s = 0; s < 2; ++s) {
            f32x4 s0 = (f32x4){0.f, 0.f, 0.f, 0.f};
            f32x4 s1 = (f32x4){0.f, 0.f, 0.f, 0.f};
            s0 = __builtin_amdgcn_mfma_f32_16x16x32_bf16(kf[0][0], qf[s][0], s0, 0, 0, 0);
            s0 = __builtin_amdgcn_mfma_f32_16x16x32_bf16(kf[0][1], qf[s][1], s0, 0, 0, 0);
            s1 = __builtin_amdgcn_mfma_f32_16x16x32_bf16(kf[1][0], qf[s][0], s1, 0, 0, 0);
            s1 = __builtin_amdgcn_mfma_f32_16x16x32_bf16(kf[1][1], qf[s][1], s1, 0, 0, 0);

            float p0[4], p1[4];
#pragma unroll
            for (int r = 0; r < 4; ++r) {
                p0[r] = fast_exp2(s0[r]);
                p1[r] = fast_exp2(s1[r]);
            }
            lr[s] += (p0[0] + p0[1]) + (p0[2] + p0[3]) + (p1[0] + p1[1]) + (p1[2] + p1[3]);

            union { bf16x8 v8; unsigned d[4]; } P;
            P.d[0] = pack_bf_trunc(p0[0], p0[1]);
            P.d[1] = pack_bf_trunc(p0[2], p0[3]);
            P.d[2] = pack_bf_trunc(p1[0], p1[1]);
            P.d[3] = pack_bf_trunc(p1[2], p1[3]);
#pragma unroll
            for (int c = 0; c < 4; ++c)
                Oc[s][c] = __builtin_amdgcn_mfma_f32_16x16x32_bf16(vf[c], P.v8, Oc[s][c], 0, 0, 0);
        }
    }

#pragma unroll
    for (int s = 0; s < 2; ++s) {
        lr[s] += __shfl_xor(lr[s], 16);
        lr[s] += __shfl_xor(lr[s], 32);
    }

    __syncthreads();
    float* exch = (float*)SL;
    float* lx   = ((float*)SL) + 128 * 68;
    if (grp == 1) {
#pragma unroll
        for (int s = 0; s < 2; ++s) {
            const int lq = wq * 32 + 16 * s + l16;
#pragma unroll
            for (int c = 0; c < 4; ++c)
                *(f32x4*)&exch[lq * 68 + 16 * c + 4 * quad] = Oc[s][c];
            if (quad == 0) lx[lq] = lr[s];
        }
    }
    __syncthreads();
    if (grp == 0) {
        const int b = bh >> 2, h = bh & 3;
#pragma unroll
        for (int s = 0; s < 2; ++s) {
            const int lq = wq * 32 + 16 * s + l16;
            const float linv = 1.0f / (lr[s] + lx[lq]);
            ushort* dst = out + (size_t)(b * NSEQ + blockIdx.x * 128 + lq) * HID + h * DHD;
#pragma unroll
            for (int c = 0; c < 4; ++c) {
                const f32x4 o1 = *(const f32x4*)&exch[lq * 68 + 16 * c + 4 * quad];
                u16x4 w;
#pragma unroll
                for (int r = 0; r < 4; ++r) w[r] = f2bf((Oc[s][c][r] + o1[r]) * linv);
                *(u16x4*)(dst + 16 * c + quad * 4) = w;
            }
        }
    }
}

// ---------------------------------------------------------------------------
// Kernel 4: out_proj + bias + residual + LayerNorm -- 16-ROW BLOCKS.
// Was 512 blocks (2/CU, 2 waves/SIMD) of dependent L2-load->MFMA chains ->
// the round-0 attn starvation profile. Now 1024 blocks (4/CU), half the
// per-block work, half the LDS. Math per row unchanged.
// ---------------------------------------------------------------------------
__global__ __launch_bounds__(256) void oproj_ln_mfma(
        const ushort* __restrict__ abuf, const float* __restrict__ Qin,
        const ushort* __restrict__ WoB, const float* __restrict__ bo,
        const float* __restrict__ g, const float* __restrict__ be,
        float* __restrict__ out) {
    __shared__ float yt[16][260];
    const int wv = threadIdx.x >> 6, lane = threadIdx.x & 63;
    const int l16 = lane & 15, quad = lane >> 4;
    const int m0 = blockIdx.x * 16;
    const int n0 = wv * 64;

    f32x4 acc[4];
#pragma unroll
    for (int c = 0; c < 4; ++c) acc[c] = (f32x4){0.f, 0.f, 0.f, 0.f};

    for (int kk = 0; kk < HID; kk += 32) {
        const bf16x8 af = *(const bf16x8*)(abuf + (size_t)(m0 + l16) * HID + kk + quad * 8);
        bf16x8 bf[4];
#pragma unroll
        for (int c = 0; c < 4; ++c)
            bf[c] = *(const bf16x8*)(WoB + (size_t)(n0 + 16 * c + l16) * HID + kk + quad * 8);
#pragma unroll
        for (int c = 0; c < 4; ++c)
            acc[c] = __builtin_amdgcn_mfma_f32_16x16x32_bf16(af, bf[c], acc[c], 0, 0, 0);
    }

#pragma unroll
    for (int c = 0; c < 4; ++c) {
        const int col = n0 + 16 * c + l16;
        const float bv = bo[col];
#pragma unroll
        for (int r = 0; r < 4; ++r) {
            const int row = quad * 4 + r;
            yt[row][col] = acc[c][r] + bv + Qin[(size_t)(m0 + row) * HID + col];
        }
    }
    __syncthreads();

    float gv[4], bev[4];
#pragma unroll
    for (int u = 0; u < 4; ++u) { gv[u] = g[lane + 64 * u]; bev[u] = be[lane + 64 * u]; }

    for (int rr = 0; rr < 4; ++rr) {
        const int row = wv * 4 + rr;
        float sm = 0.f, ssq = 0.f;
        float yv[4];
#pragma unroll
        for (int u = 0; u < 4; ++u) {
            yv[u] = yt[row][lane + 64 * u];
            sm += yv[u]; ssq += yv[u] * yv[u];
        }
#pragma unroll
        for (int off = 32; off >= 1; off >>= 1) {
            sm += __shfl_xor(sm, off);
            ssq += __shfl_xor(ssq, off);
        }
        const float mu = sm * (1.f / 256.f);
        const float rs = rsqrtf(fmaxf(ssq * (1.f / 256.f) - mu * mu, 0.f) + 1e-5f);
        float* dst = out + (size_t)(m0 + row) * HID;
#pragma unroll
        for (int u = 0; u < 4; ++u)
            dst[lane + 64 * u] = (yv[u] - mu) * rs * gv[u] + bev[u];
    }
}

// ---------------------------------------------------------------------------
extern "C" void kernel_launch(void* const* d_in, const int* in_sizes, int n_in,
                              void* d_out, int out_size, void* d_ws, size_t ws_size,
                              hipStream_t stream) {
    const float* inputs       = (const float*)d_in[0];
    const float* Q_in         = (const float*)d_in[1];
    const float* input_coords = (const float*)d_in[2];
    const float* Q_in_coords  = (const float*)d_in[3];
    const float* Wq           = (const float*)d_in[4];
    const float* Wk           = (const float*)d_in[5];
    const float* Wv           = (const float*)d_in[6];
    const float* in_proj_w    = (const float*)d_in[7];
    const float* in_proj_b    = (const float*)d_in[8];
    const float* out_proj_w   = (const float*)d_in[9];
    const float* out_proj_b   = (const float*)d_in[10];
    const float* ln_g         = (const float*)d_in[11];
    const float* ln_b         = (const float*)d_in[12];
    const float* pe_w1        = (const float*)d_in[13];
    const float* pe_b1        = (const float*)d_in[14];
    const float* pe_w2        = (const float*)d_in[15];
    const float* pe_b2        = (const float*)d_in[16];

    char* ws = (char*)d_ws;
    ushort* Wb   = (ushort*)(ws);              // 768*288*2     = 442368
    ushort* WoB  = (ushort*)(ws + 442368);     // 256*256*2     = 131072
    ushort* qp   = (ushort*)(ws + 573440);     // 16384*288*2   = 9437184
    ushort* ip   = (ushort*)(ws + 10010624);   // 9437184
    ushort* qbuf = (ushort*)(ws + 19447808);   // 8388608
    ushort* kbuf = (ushort*)(ws + 27836416);   // 8388608
    ushort* vbuf = (ushort*)(ws + 36225024);   // 8388608 (transposed [bh][64][n])
    ushort* abuf = (ushort*)(ws + 44613632);   // 8388608 -> end 53002240 bytes

    prep_kernel<<<5952, 256, 0, stream>>>(input_coords, Q_in_coords,
                                          pe_w1, pe_b1, pe_w2, pe_b2,
                                          inputs, Q_in, in_proj_w,
                                          Wq, Wk, Wv, out_proj_w,
                                          ip, qp, Wb, WoB);
    qkv_mfma<<<dim3(128, 12), 256, 0, stream>>>(qp, ip, Wb, in_proj_b,
                                                qbuf, kbuf, vbuf);
    attn_kernel<<<dim3(16, 32), 512, 0, stream>>>(qbuf, kbuf, vbuf, abuf);
    oproj_ln_mfma<<<1024, 256, 0, stream>>>(abuf, Q_in, WoB, out_proj_b,
                                            ln_g, ln_b, (float*)d_out);
}

// Round 10
// 218.470 us; speedup vs baseline: 1.0300x; 1.0300x over previous
//
#include <hip/hip_runtime.h>
#include <math.h>

#define HID 256
#define CIN 288      // HID + POS
#define NTOK 16384   // B*N
#define NSEQ 2048
#define NH 4
#define DHD 64
#define TWO_PI 6.2831853071795864769f

typedef __attribute__((ext_vector_type(8))) short bf16x8;
typedef __attribute__((ext_vector_type(4))) float f32x4;
typedef __attribute__((ext_vector_type(4))) unsigned short u16x4;

__device__ __forceinline__ ushort f2bf(float x) {
    unsigned u = __float_as_uint(x);
    u = (u + 0x7FFFu + ((u >> 16) & 1u)) >> 16;
    return (ushort)u;
}

__device__ __forceinline__ float fast_exp2(float x) {
    return __builtin_amdgcn_exp2f(x);   // v_exp_f32
}

// pack two fp32 -> one dword of truncated bf16 (lo=a, hi=b) via v_perm_b32
__device__ __forceinline__ unsigned pack_bf_trunc(float a, float b) {
    return __builtin_amdgcn_perm(__float_as_uint(b), __float_as_uint(a), 0x07060302u);
}

// async global->LDS, 16 B per lane: LDS dst = base + lane*16 (wave-uniform base)
__device__ __forceinline__ void gload_lds16(const ushort* g, ushort* l) {
    __builtin_amdgcn_global_load_lds(
        (const __attribute__((address_space(1))) unsigned*)g,
        (__attribute__((address_space(3))) unsigned*)l, 16, 0, 0);
}

// LDS chunk swizzle for 128B rows (8 x 16B chunks/row): uniform bank classes
__device__ __forceinline__ int sw(int row) {
    return (((row >> 3) << 1) ^ row) & 7;
}

// chunk swizzle for 64B rows (4 x 16B chunks/row)
__device__ __forceinline__ int swv(int row) {
    return ((row & 3) ^ ((row >> 2) & 3));
}

// ---------------------------------------------------------------------------
// Kernel 1 (MERGED PREP): fuse_w | pos_mlp | cast_wo | cast_x in ONE grid.
// OCCUPANCY FIX: prep has been ~55us steady-state in every round with
// OccupancyPercent ~30% (VGPR 76 -> 6 waves/SIMD) while every phase is a
// memory-latency chain. __launch_bounds__(256, 8) caps VGPR at 64 -> 8
// blocks/CU (32 waves, LDS allows 9). To fit 64 VGPR, pos_mlp layer-2 is
// computed in TWO passes of part[16] (identical per-output summation trees
// -> bit-identical results; threads p<4 store outputs 0..15, p>=4 store
// 16..31). fuse_w gets unroll 16 (32 loads in flight/thread, was 8).
// Block order: longest-latency-chain blocks (fuse_w) first.
//   [0,768)      fuse_w    (768 blocks; 256 thr, t<32 also does col 256+t)
//   [768,1792)   pos_mlp   (8 thr/token, 32 tokens/block)
//   [1792,1856)  cast_wo   (64 blocks)
//   [1856,5952)  cast_x    (4096 blocks)
// DIAGNOSTIC: expect VGPR<=64, Occupancy>=55. If dur stays >=50us with high
// occupancy, prep is issue/fabric-bound -> next step eliminates cast_x.
// ---------------------------------------------------------------------------
__global__ __launch_bounds__(256, 8) void prep_kernel(
        const float* __restrict__ icoords, const float* __restrict__ qcoords,
        const float* __restrict__ w1, const float* __restrict__ b1,
        const float* __restrict__ w2, const float* __restrict__ b2,
        const float* __restrict__ X, const float* __restrict__ Qin,
        const float* __restrict__ inW,
        const float* __restrict__ Wq, const float* __restrict__ Wk,
        const float* __restrict__ Wv,
        const float* __restrict__ Wo,
        ushort* __restrict__ ip, ushort* __restrict__ qp,
        ushort* __restrict__ Wb, ushort* __restrict__ WoB) {
    __shared__ float SMEM[4160];
    const int blk = blockIdx.x;
    const int t = threadIdx.x;

    if (blk < 768) {
        // ---------------- fuse_w ----------------
        float* wrow = SMEM;
        const int o = blk & 255;
        const int mat = blk >> 8;
        wrow[t] = inW[(mat * 256 + o) * 256 + t];
        __syncthreads();
        const float* Wm = (mat == 0) ? Wq : ((mat == 1) ? Wk : Wv);
        const int t2 = 256 + (t & 31);
        float acc0 = 0.f, acc1 = 0.f;
#pragma unroll 16
        for (int h = 0; h < 256; ++h) {
            const float wh = wrow[h];
            acc0 += wh * Wm[h * CIN + t];
            acc1 += wh * Wm[h * CIN + t2];
        }
        ushort* dst = Wb + (size_t)(mat * 256 + o) * CIN;
        dst[t] = f2bf(acc0);
        if (t < 32) dst[t2] = f2bf(acc1);
    } else if (blk < 1792) {
        // ---------------- pos_mlp (8 threads per token) ----------------
        float* sw1t = SMEM;            // [96][32] transposed
        float* sb1  = SMEM + 3072;     // [32]
        float* sw2  = SMEM + 3104;     // [32][32]
        float* sb2  = SMEM + 4128;     // [32]
        for (int i = t; i < 96 * 32; i += 256) {
            const int e = i >> 5, r = i & 31;
            sw1t[i] = w1[r * 96 + e];
        }
        for (int i = t; i < 32 * 32; i += 256) sw2[i] = w2[i];
        if (t < 32) { sb1[t] = b1[t]; sb2[t] = b2[t]; }
        __syncthreads();

        const int p = t & 7;                       // owns h rows 4p..4p+3
        const int tok = (blk - 768) * 32 + (t >> 3);
        const int which = tok >> 14;
        const int m = tok & (NTOK - 1);
        const float* cr = (which ? qcoords : icoords) + m * 4;
        const float x = cr[1] * TWO_PI;
        const float y = cr[2] * TWO_PI;
        const float z = cr[3] * TWO_PI;

        f32x4 h = *(const f32x4*)&sb1[4 * p];

        for (int jj = 0; jj < 16; ++jj) {
            const float inv = 1.0f / (1.0f + 0.0625f * (float)jj);
            const float xs = x * inv, ys = y * inv, zs = z * inv;
            const float cx = __cosf(xs);
            float vals[6];
            int idx[6];
            vals[0] = __sinf(ys);  idx[0] = 2 * jj;
            vals[1] = __cosf(ys);  idx[1] = 2 * jj + 1;
            vals[2] = __sinf(xs);  idx[2] = 32 + 2 * jj;
            vals[3] = cx;          idx[3] = 32 + 2 * jj + 1;
            vals[4] = __sinf(zs);  idx[4] = 64 + 2 * jj;
            vals[5] = cx;          idx[5] = 64 + 2 * jj + 1;   // reference bug: cos of x
#pragma unroll
            for (int u = 0; u < 6; ++u)
                h += vals[u] * *(const f32x4*)&sw1t[idx[u] * 32 + 4 * p];
        }
#pragma unroll
        for (int j = 0; j < 4; ++j) h[j] = fmaxf(h[j], 0.f);

        ushort* dst = (which ? qp : ip) + (size_t)m * CIN + 256;

        // layer 2 in two passes of 16 outputs (peak regs ~16 instead of 32)
        {
            float part[16];
#pragma unroll
            for (int c = 0; c < 16; ++c) {
                const f32x4 w4 = *(const f32x4*)&sw2[c * 32 + 4 * p];
                part[c] = (h[0] * w4[0] + h[1] * w4[1]) + (h[2] * w4[2] + h[3] * w4[3]);
            }
#pragma unroll
            for (int c = 0; c < 16; ++c) part[c] += __shfl_xor(part[c], 1);
#pragma unroll
            for (int c = 0; c < 16; ++c) part[c] += __shfl_xor(part[c], 2);
#pragma unroll
            for (int c = 0; c < 16; ++c) part[c] += __shfl_xor(part[c], 4);
            if (p < 4) {
                u16x4 w;
#pragma unroll
                for (int r = 0; r < 4; ++r) w[r] = f2bf(sb2[4 * p + r] + part[4 * p + r]);
                *(u16x4*)(dst + 4 * p) = w;
            }
        }
        {
            float part[16];
#pragma unroll
            for (int c = 0; c < 16; ++c) {
                const f32x4 w4 = *(const f32x4*)&sw2[(16 + c) * 32 + 4 * p];
                part[c] = (h[0] * w4[0] + h[1] * w4[1]) + (h[2] * w4[2] + h[3] * w4[3]);
            }
#pragma unroll
            for (int c = 0; c < 16; ++c) part[c] += __shfl_xor(part[c], 1);
#pragma unroll
            for (int c = 0; c < 16; ++c) part[c] += __shfl_xor(part[c], 2);
#pragma unroll
            for (int c = 0; c < 16; ++c) part[c] += __shfl_xor(part[c], 4);
            if (p >= 4) {
                const int pb = p - 4;
                u16x4 w;
#pragma unroll
                for (int r = 0; r < 4; ++r) w[r] = f2bf(sb2[16 + 4 * pb + r] + part[4 * pb + r]);
                *(u16x4*)(dst + 16 + 4 * pb) = w;
            }
        }
    } else if (blk < 1856) {
        // ---------------- cast_wo ----------------
        const int f = ((blk - 1792) * 256 + t) * 4;
        const float4 a = *(const float4*)(Wo + f);
        u16x4 o = {f2bf(a.x), f2bf(a.y), f2bf(a.z), f2bf(a.w)};
        *(u16x4*)(WoB + f) = o;
    } else {
        // ---------------- cast_x ----------------
        const int i = blk - 1856;
        const int which = i >> 11;
        const size_t f = ((size_t)(i & 2047) * 256 + t) * 8;
        const int row = (int)(f >> 8);
        const int col = (int)(f & 255);
        const float* src = which ? Qin : X;
        ushort* dst = which ? qp : ip;
        const float4 a = *(const float4*)(src + f);
        const float4 b = *(const float4*)(src + f + 4);
        u16x4 o0 = {f2bf(a.x), f2bf(a.y), f2bf(a.z), f2bf(a.w)};
        u16x4 o1 = {f2bf(b.x), f2bf(b.y), f2bf(b.z), f2bf(b.w)};
        *(u16x4*)(dst + (size_t)row * CIN + col) = o0;
        *(u16x4*)(dst + (size_t)row * CIN + col + 4) = o1;
    }
}

// ---------------------------------------------------------------------------
// Kernel 2: QKV projection -- counted-vmcnt pipeline (unchanged from r8).
// ---------------------------------------------------------------------------
__global__ __launch_bounds__(256) void qkv_mfma(
        const ushort* __restrict__ qp, const ushort* __restrict__ ip,
        const ushort* __restrict__ Wb, const float* __restrict__ bias,
        ushort* __restrict__ qout, ushort* __restrict__ kout, ushort* __restrict__ vout) {
    __shared__ ushort SA[3 * 6144];   // 3 x (A 8KB + B 4KB) = 36 KB
    const int wv = threadIdx.x >> 6, lane = threadIdx.x & 63;
    const int l16 = lane & 15, quad = lane >> 4;
    const int m0b = blockIdx.x * 128;
    const int y = blockIdx.y;
    const int mat = y >> 2;
    const int n0 = y * 64;
    const ushort* A = (mat == 0) ? qp : ip;

    size_t asrc[2];
    int adst[2];
#pragma unroll
    for (int i = 0; i < 2; ++i) {
        const int idx = wv * 128 + i * 64 + lane;
        const int row = idx >> 2;
        const int cc = (idx & 3) ^ ((row >> 1) & 3);
        asrc[i] = (size_t)(m0b + row) * CIN + cc * 8;
        adst[i] = (wv * 128 + i * 64) * 8;
    }
    const int bidx = wv * 64 + lane;
    const int brow = bidx >> 2;
    const int bcc = (bidx & 3) ^ ((brow >> 1) & 3);
    const size_t bsrc = (size_t)(n0 + brow) * CIN + bcc * 8;
    const int bdst = 4096 + wv * 512;

    const int rsw = quad ^ ((l16 >> 1) & 3);
    int aoff[2];
#pragma unroll
    for (int s = 0; s < 2; ++s)
        aoff[s] = ((32 * wv + 16 * s + l16) * 4 + rsw) * 8;
    int boff[4];
#pragma unroll
    for (int c = 0; c < 4; ++c)
        boff[c] = 4096 + ((16 * c + l16) * 4 + rsw) * 8;

    f32x4 acc[2][4];
#pragma unroll
    for (int s = 0; s < 2; ++s)
#pragma unroll
        for (int c = 0; c < 4; ++c) acc[s][c] = (f32x4){0.f, 0.f, 0.f, 0.f};

#pragma unroll
    for (int pt = 0; pt < 2; ++pt) {
        ushort* db = SA + pt * 6144;
        gload_lds16(A + asrc[0] + pt * 32, db + adst[0]);
        gload_lds16(A + asrc[1] + pt * 32, db + adst[1]);
        gload_lds16(Wb + bsrc + pt * 32, db + bdst);
    }

    int co = 0, po = 12288;
    for (int t = 0; t < 9; ++t) {
        if (t < 8) asm volatile("s_waitcnt vmcnt(3)" ::: "memory");
        else       asm volatile("s_waitcnt vmcnt(0)" ::: "memory");
        __builtin_amdgcn_s_barrier();

        if (t + 2 < 9) {
            ushort* db = SA + po;
            gload_lds16(A + asrc[0] + (t + 2) * 32, db + adst[0]);
            gload_lds16(A + asrc[1] + (t + 2) * 32, db + adst[1]);
            gload_lds16(Wb + bsrc + (t + 2) * 32, db + bdst);
            po = (po == 12288) ? 0 : po + 6144;
        }
        const ushort* buf = SA + co;
        co = (co == 12288) ? 0 : co + 6144;

        bf16x8 af[2], bf[4];
#pragma unroll
        for (int s = 0; s < 2; ++s)
            af[s] = *(const bf16x8*)(buf + aoff[s]);
#pragma unroll
        for (int c = 0; c < 4; ++c)
            bf[c] = *(const bf16x8*)(buf + boff[c]);
        if (mat < 2) {
#pragma unroll
            for (int s = 0; s < 2; ++s)
#pragma unroll
                for (int c = 0; c < 4; ++c)
                    acc[s][c] = __builtin_amdgcn_mfma_f32_16x16x32_bf16(bf[c], af[s], acc[s][c], 0, 0, 0);
        } else {
#pragma unroll
            for (int s = 0; s < 2; ++s)
#pragma unroll
                for (int c = 0; c < 4; ++c)
                    acc[s][c] = __builtin_amdgcn_mfma_f32_16x16x32_bf16(af[s], bf[c], acc[s][c], 0, 0, 0);
        }
    }

    const int h = y & 3;
    const int m0 = m0b + wv * 32;
    if (mat < 2) {
        const float scale = (mat == 0) ? (0.125f * 1.44269504088896f) : 1.0f;
        ushort* out = (mat == 0) ? qout : kout;
#pragma unroll
        for (int s = 0; s < 2; ++s) {
            const int tokm = m0 + 16 * s + l16;
            const int b = tokm >> 11, nn = tokm & (NSEQ - 1);
#pragma unroll
            for (int c = 0; c < 4; ++c) {
                const f32x4 b4 = *(const f32x4*)&bias[n0 + 16 * c + quad * 4];
                u16x4 w;
#pragma unroll
                for (int r = 0; r < 4; ++r) w[r] = f2bf((acc[s][c][r] + b4[r]) * scale);
                *(u16x4*)(out + ((size_t)(b * NH + h) * NSEQ + nn) * DHD + 16 * c + quad * 4) = w;
            }
        }
    } else {
#pragma unroll
        for (int s = 0; s < 2; ++s) {
            const int tok0 = m0 + 16 * s + quad * 4;
            const int b = tok0 >> 11, nn0 = tok0 & (NSEQ - 1);
#pragma unroll
            for (int c = 0; c < 4; ++c) {
                const int d = 16 * c + l16;
                const float bv = bias[n0 + d];
                u16x4 w;
#pragma unroll
                for (int r = 0; r < 4; ++r) w[r] = f2bf(acc[s][c][r] + bv);
                *(u16x4*)(vout + ((size_t)(b * NH + h) * DHD + d) * NSEQ + nn0) = w;
            }
        }
    }
}

// ---------------------------------------------------------------------------
// Kernel 3: MFMA flash attention (unchanged from r8).
// ---------------------------------------------------------------------------
__global__ __launch_bounds__(512, 4) void attn_kernel(
        const ushort* __restrict__ q, const ushort* __restrict__ k,
        const ushort* __restrict__ v, ushort* __restrict__ out) {
    __shared__ ushort SL[24576];   // 48 KB
    const int bh = blockIdx.y;
    const int wv = threadIdx.x >> 6;     // 0..7
    const int grp = wv >> 2;             // key half
    const int wq = wv & 3;               // q sub-block within group
    const int lane = threadIdx.x & 63;
    const int l16 = lane & 15, quad = lane >> 4;
    const int q0 = blockIdx.x * 128 + wq * 32;

    const ushort* qb = q + (size_t)bh * NSEQ * DHD;
    const ushort* kb = k + (size_t)bh * NSEQ * DHD + (size_t)(grp * 1024) * DHD;
    const ushort* vb = v + (size_t)bh * DHD * NSEQ + grp * 1024;
    ushort* SG = SL + grp * 12288;

    bf16x8 qf[2][2];
#pragma unroll
    for (int s = 0; s < 2; ++s)
#pragma unroll
        for (int hh = 0; hh < 2; ++hh)
            qf[s][hh] = *(const bf16x8*)(qb + (size_t)(q0 + 16 * s + l16) * DHD + 32 * hh + quad * 8);

    const int krow_s = 8 * wq + (lane >> 3);
    const int kcg = (lane & 7) ^ sw(krow_s);
    const size_t ksrc = (size_t)krow_s * DHD + kcg * 8;
    const int kdst = wq * 512;
    const int vrow_s = 16 * wq + (lane >> 2);
    const int vcg = (lane & 3) ^ swv(vrow_s);
    const size_t vsrc = (size_t)vrow_s * NSEQ + vcg * 8;
    const int vdst = wq * 512;

    const int krow = 8 * (l16 >> 2) + (l16 & 3);
    int koff[2][2];
    int voff[4];
#pragma unroll
    for (int m = 0; m < 2; ++m) {
        const int row = krow + 4 * m;
#pragma unroll
        for (int hh = 0; hh < 2; ++hh)
            koff[m][hh] = row * 64 + (((hh * 4 + quad) ^ sw(row))) * 8;
    }
#pragma unroll
    for (int c = 0; c < 4; ++c) {
        const int d = 16 * c + l16;
        voff[c] = 2048 + d * 32 + ((quad ^ swv(d))) * 8;
    }

    f32x4 Oc[2][4];
#pragma unroll
    for (int s = 0; s < 2; ++s)
#pragma unroll
        for (int c = 0; c < 4; ++c) Oc[s][c] = (f32x4){0.f, 0.f, 0.f, 0.f};
    float lr[2] = {0.f, 0.f};

#pragma unroll
    for (int pt = 0; pt < 2; ++pt) {
        ushort* db = SG + pt * 4096;
        gload_lds16(kb + (size_t)(pt * 32) * DHD + ksrc, db + kdst);
        gload_lds16(vb + pt * 32 + vsrc, db + 2048 + vdst);
    }

    int co = 0, po = 8192;
    for (int t = 0; t < 32; ++t) {
        if (t < 31) asm volatile("s_waitcnt vmcnt(2)" ::: "memory");
        else        asm volatile("s_waitcnt vmcnt(0)" ::: "memory");
        __builtin_amdgcn_s_barrier();

        if (t < 30) {
            ushort* db = SG + po;
            gload_lds16(kb + (size_t)((t + 2) * 32) * DHD + ksrc, db + kdst);
            gload_lds16(vb + (t + 2) * 32 + vsrc, db + 2048 + vdst);
            po = (po == 8192) ? 0 : po + 4096;
        }
        const ushort* buf = SG + co;
        co = (co == 8192) ? 0 : co + 4096;

        bf16x8 kf[2][2], vf[4];
#pragma unroll
        for (int m = 0; m < 2; ++m)
#pragma unroll
            for (int hh = 0; hh < 2; ++hh)
                kf[m][hh] = *(const bf16x8*)(buf + koff[m][hh]);
#pragma unroll
        for (int c = 0; c < 4; ++c)
            vf[c] = *(const bf16x8*)(buf + voff[c]);

#pragma unroll
        for (int s = 0; s < 2; ++s) {
            f32x4 s0 = (f32x4){0.f, 0.f, 0.f, 0.f};
            f32x4 s1 = (f32x4){0.f, 0.f, 0.f, 0.f};
            s0 = __builtin_amdgcn_mfma_f32_16x16x32_bf16(kf[0][0], qf[s][0], s0, 0, 0, 0);
            s0 = __builtin_amdgcn_mfma_f32_16x16x32_bf16(kf[0][1], qf[s][1], s0, 0, 0, 0);
            s1 = __builtin_amdgcn_mfma_f32_16x16x32_bf16(kf[1][0], qf[s][0], s1, 0, 0, 0);
            s1 = __builtin_amdgcn_mfma_f32_16x16x32_bf16(kf[1][1], qf[s][1], s1, 0, 0, 0);

            float p0[4], p1[4];
#pragma unroll
            for (int r = 0; r < 4; ++r) {
                p0[r] = fast_exp2(s0[r]);
                p1[r] = fast_exp2(s1[r]);
            }
            lr[s] += (p0[0] + p0[1]) + (p0[2] + p0[3]) + (p1[0] + p1[1]) + (p1[2] + p1[3]);

            union { bf16x8 v8; unsigned d[4]; } P;
            P.d[0] = pack_bf_trunc(p0[0], p0[1]);
            P.d[1] = pack_bf_trunc(p0[2], p0[3]);
            P.d[2] = pack_bf_trunc(p1[0], p1[1]);
            P.d[3] = pack_bf_trunc(p1[2], p1[3]);
#pragma unroll
            for (int c = 0; c < 4; ++c)
                Oc[s][c] = __builtin_amdgcn_mfma_f32_16x16x32_bf16(vf[c], P.v8, Oc[s][c], 0, 0, 0);
        }
    }

#pragma unroll
    for (int s = 0; s < 2; ++s) {
        lr[s] += __shfl_xor(lr[s], 16);
        lr[s] += __shfl_xor(lr[s], 32);
    }

    __syncthreads();
    float* exch = (float*)SL;
    float* lx   = ((float*)SL) + 128 * 68;
    if (grp == 1) {
#pragma unroll
        for (int s = 0; s < 2; ++s) {
            const int lq = wq * 32 + 16 * s + l16;
#pragma unroll
            for (int c = 0; c < 4; ++c)
                *(f32x4*)&exch[lq * 68 + 16 * c + 4 * quad] = Oc[s][c];
            if (quad == 0) lx[lq] = lr[s];
        }
    }
    __syncthreads();
    if (grp == 0) {
        const int b = bh >> 2, h = bh & 3;
#pragma unroll
        for (int s = 0; s < 2; ++s) {
            const int lq = wq * 32 + 16 * s + l16;
            const float linv = 1.0f / (lr[s] + lx[lq]);
            ushort* dst = out + (size_t)(b * NSEQ + blockIdx.x * 128 + lq) * HID + h * DHD;
#pragma unroll
            for (int c = 0; c < 4; ++c) {
                const f32x4 o1 = *(const f32x4*)&exch[lq * 68 + 16 * c + 4 * quad];
                u16x4 w;
#pragma unroll
                for (int r = 0; r < 4; ++r) w[r] = f2bf((Oc[s][c][r] + o1[r]) * linv);
                *(u16x4*)(dst + 16 * c + quad * 4) = w;
            }
        }
    }
}

// ---------------------------------------------------------------------------
// Kernel 4: out_proj + bias + residual + LayerNorm (unchanged from r8).
// ---------------------------------------------------------------------------
__global__ __launch_bounds__(256) void oproj_ln_mfma(
        const ushort* __restrict__ abuf, const float* __restrict__ Qin,
        const ushort* __restrict__ WoB, const float* __restrict__ bo,
        const float* __restrict__ g, const float* __restrict__ be,
        float* __restrict__ out) {
    __shared__ float yt[16][260];
    const int wv = threadIdx.x >> 6, lane = threadIdx.x & 63;
    const int l16 = lane & 15, quad = lane >> 4;
    const int m0 = blockIdx.x * 16;
    const int n0 = wv * 64;

    f32x4 acc[4];
#pragma unroll
    for (int c = 0; c < 4; ++c) acc[c] = (f32x4){0.f, 0.f, 0.f, 0.f};

    for (int kk = 0; kk < HID; kk += 32) {
        const bf16x8 af = *(const bf16x8*)(abuf + (size_t)(m0 + l16) * HID + kk + quad * 8);
        bf16x8 bf[4];
#pragma unroll
        for (int c = 0; c < 4; ++c)
            bf[c] = *(const bf16x8*)(WoB + (size_t)(n0 + 16 * c + l16) * HID + kk + quad * 8);
#pragma unroll
        for (int c = 0; c < 4; ++c)
            acc[c] = __builtin_amdgcn_mfma_f32_16x16x32_bf16(af, bf[c], acc[c], 0, 0, 0);
    }

#pragma unroll
    for (int c = 0; c < 4; ++c) {
        const int col = n0 + 16 * c + l16;
        const float bv = bo[col];
#pragma unroll
        for (int r = 0; r < 4; ++r) {
            const int row = quad * 4 + r;
            yt[row][col] = acc[c][r] + bv + Qin[(size_t)(m0 + row) * HID + col];
        }
    }
    __syncthreads();

    float gv[4], bev[4];
#pragma unroll
    for (int u = 0; u < 4; ++u) { gv[u] = g[lane + 64 * u]; bev[u] = be[lane + 64 * u]; }

    for (int rr = 0; rr < 4; ++rr) {
        const int row = wv * 4 + rr;
        float sm = 0.f, ssq = 0.f;
        float yv[4];
#pragma unroll
        for (int u = 0; u < 4; ++u) {
            yv[u] = yt[row][lane + 64 * u];
            sm += yv[u]; ssq += yv[u] * yv[u];
        }
#pragma unroll
        for (int off = 32; off >= 1; off >>= 1) {
            sm += __shfl_xor(sm, off);
            ssq += __shfl_xor(ssq, off);
        }
        const float mu = sm * (1.f / 256.f);
        const float rs = rsqrtf(fmaxf(ssq * (1.f / 256.f) - mu * mu, 0.f) + 1e-5f);
        float* dst = out + (size_t)(m0 + row) * HID;
#pragma unroll
        for (int u = 0; u < 4; ++u)
            dst[lane + 64 * u] = (yv[u] - mu) * rs * gv[u] + bev[u];
    }
}

// ---------------------------------------------------------------------------
extern "C" void kernel_launch(void* const* d_in, const int* in_sizes, int n_in,
                              void* d_out, int out_size, void* d_ws, size_t ws_size,
                              hipStream_t stream) {
    const float* inputs       = (const float*)d_in[0];
    const float* Q_in         = (const float*)d_in[1];
    const float* input_coords = (const float*)d_in[2];
    const float* Q_in_coords  = (const float*)d_in[3];
    const float* Wq           = (const float*)d_in[4];
    const float* Wk           = (const float*)d_in[5];
    const float* Wv           = (const float*)d_in[6];
    const float* in_proj_w    = (const float*)d_in[7];
    const float* in_proj_b    = (const float*)d_in[8];
    const float* out_proj_w   = (const float*)d_in[9];
    const float* out_proj_b   = (const float*)d_in[10];
    const float* ln_g         = (const float*)d_in[11];
    const float* ln_b         = (const float*)d_in[12];
    const float* pe_w1        = (const float*)d_in[13];
    const float* pe_b1        = (const float*)d_in[14];
    const float* pe_w2        = (const float*)d_in[15];
    const float* pe_b2        = (const float*)d_in[16];

    char* ws = (char*)d_ws;
    ushort* Wb   = (ushort*)(ws);              // 768*288*2     = 442368
    ushort* WoB  = (ushort*)(ws + 442368);     // 256*256*2     = 131072
    ushort* qp   = (ushort*)(ws + 573440);     // 16384*288*2   = 9437184
    ushort* ip   = (ushort*)(ws + 10010624);   // 9437184
    ushort* qbuf = (ushort*)(ws + 19447808);   // 8388608
    ushort* kbuf = (ushort*)(ws + 27836416);   // 8388608
    ushort* vbuf = (ushort*)(ws + 36225024);   // 8388608 (transposed [bh][64][n])
    ushort* abuf = (ushort*)(ws + 44613632);   // 8388608 -> end 53002240 bytes

    prep_kernel<<<5952, 256, 0, stream>>>(input_coords, Q_in_coords,
                                          pe_w1, pe_b1, pe_w2, pe_b2,
                                          inputs, Q_in, in_proj_w,
                                          Wq, Wk, Wv, out_proj_w,
                                          ip, qp, Wb, WoB);
    qkv_mfma<<<dim3(128, 12), 256, 0, stream>>>(qp, ip, Wb, in_proj_b,
                                                qbuf, kbuf, vbuf);
    attn_kernel<<<dim3(16, 32), 512, 0, stream>>>(qbuf, kbuf, vbuf, abuf);
    oproj_ln_mfma<<<1024, 256, 0, stream>>>(abuf, Q_in, WoB, out_proj_b,
                                            ln_g, ln_b, (float*)d_out);
}

// Round 11
// 214.430 us; speedup vs baseline: 1.0494x; 1.0188x over previous
//
#include <hip/hip_runtime.h>
#include <math.h>

#define HID 256
#define CIN 288      // HID + POS
#define NTOK 16384   // B*N
#define NSEQ 2048
#define NH 4
#define DHD 64
#define TWO_PI 6.2831853071795864769f

typedef __attribute__((ext_vector_type(8))) short bf16x8;
typedef __attribute__((ext_vector_type(4))) float f32x4;
typedef __attribute__((ext_vector_type(4))) unsigned short u16x4;

__device__ __forceinline__ ushort f2bf(float x) {
    unsigned u = __float_as_uint(x);
    u = (u + 0x7FFFu + ((u >> 16) & 1u)) >> 16;
    return (ushort)u;
}

__device__ __forceinline__ float fast_exp2(float x) {
    return __builtin_amdgcn_exp2f(x);   // v_exp_f32
}

// pack two fp32 -> one dword of truncated bf16 (lo=a, hi=b) via v_perm_b32
__device__ __forceinline__ unsigned pack_bf_trunc(float a, float b) {
    return __builtin_amdgcn_perm(__float_as_uint(b), __float_as_uint(a), 0x07060302u);
}

// async global->LDS, 16 B per lane: LDS dst = base + lane*16 (wave-uniform base)
__device__ __forceinline__ void gload_lds16(const ushort* g, ushort* l) {
    __builtin_amdgcn_global_load_lds(
        (const __attribute__((address_space(1))) unsigned*)g,
        (__attribute__((address_space(3))) unsigned*)l, 16, 0, 0);
}

// LDS chunk swizzle for 128B rows (8 x 16B chunks/row): uniform bank classes
__device__ __forceinline__ int sw(int row) {
    return (((row >> 3) << 1) ^ row) & 7;
}

// chunk swizzle for 64B rows (4 x 16B chunks/row)
__device__ __forceinline__ int swv(int row) {
    return ((row & 3) ^ ((row >> 2) & 3));
}

// ---------------------------------------------------------------------------
// Kernel 1 (MERGED PREP): fuse_w | pos_mlp | cast_wo | cast_x (unchanged from
// round 9/10 -- the launch_bounds(256,8) occupancy fix took prep below the
// 42us fill cutoff; VGPR<=64, no spill).
// ---------------------------------------------------------------------------
__global__ __launch_bounds__(256, 8) void prep_kernel(
        const float* __restrict__ icoords, const float* __restrict__ qcoords,
        const float* __restrict__ w1, const float* __restrict__ b1,
        const float* __restrict__ w2, const float* __restrict__ b2,
        const float* __restrict__ X, const float* __restrict__ Qin,
        const float* __restrict__ inW,
        const float* __restrict__ Wq, const float* __restrict__ Wk,
        const float* __restrict__ Wv,
        const float* __restrict__ Wo,
        ushort* __restrict__ ip, ushort* __restrict__ qp,
        ushort* __restrict__ Wb, ushort* __restrict__ WoB) {
    __shared__ float SMEM[4160];
    const int blk = blockIdx.x;
    const int t = threadIdx.x;

    if (blk < 768) {
        // ---------------- fuse_w ----------------
        float* wrow = SMEM;
        const int o = blk & 255;
        const int mat = blk >> 8;
        wrow[t] = inW[(mat * 256 + o) * 256 + t];
        __syncthreads();
        const float* Wm = (mat == 0) ? Wq : ((mat == 1) ? Wk : Wv);
        const int t2 = 256 + (t & 31);
        float acc0 = 0.f, acc1 = 0.f;
#pragma unroll 16
        for (int h = 0; h < 256; ++h) {
            const float wh = wrow[h];
            acc0 += wh * Wm[h * CIN + t];
            acc1 += wh * Wm[h * CIN + t2];
        }
        ushort* dst = Wb + (size_t)(mat * 256 + o) * CIN;
        dst[t] = f2bf(acc0);
        if (t < 32) dst[t2] = f2bf(acc1);
    } else if (blk < 1792) {
        // ---------------- pos_mlp (8 threads per token) ----------------
        float* sw1t = SMEM;            // [96][32] transposed
        float* sb1  = SMEM + 3072;     // [32]
        float* sw2  = SMEM + 3104;     // [32][32]
        float* sb2  = SMEM + 4128;     // [32]
        for (int i = t; i < 96 * 32; i += 256) {
            const int e = i >> 5, r = i & 31;
            sw1t[i] = w1[r * 96 + e];
        }
        for (int i = t; i < 32 * 32; i += 256) sw2[i] = w2[i];
        if (t < 32) { sb1[t] = b1[t]; sb2[t] = b2[t]; }
        __syncthreads();

        const int p = t & 7;                       // owns h rows 4p..4p+3
        const int tok = (blk - 768) * 32 + (t >> 3);
        const int which = tok >> 14;
        const int m = tok & (NTOK - 1);
        const float* cr = (which ? qcoords : icoords) + m * 4;
        const float x = cr[1] * TWO_PI;
        const float y = cr[2] * TWO_PI;
        const float z = cr[3] * TWO_PI;

        f32x4 h = *(const f32x4*)&sb1[4 * p];

        for (int jj = 0; jj < 16; ++jj) {
            const float inv = 1.0f / (1.0f + 0.0625f * (float)jj);
            const float xs = x * inv, ys = y * inv, zs = z * inv;
            const float cx = __cosf(xs);
            float vals[6];
            int idx[6];
            vals[0] = __sinf(ys);  idx[0] = 2 * jj;
            vals[1] = __cosf(ys);  idx[1] = 2 * jj + 1;
            vals[2] = __sinf(xs);  idx[2] = 32 + 2 * jj;
            vals[3] = cx;          idx[3] = 32 + 2 * jj + 1;
            vals[4] = __sinf(zs);  idx[4] = 64 + 2 * jj;
            vals[5] = cx;          idx[5] = 64 + 2 * jj + 1;   // reference bug: cos of x
#pragma unroll
            for (int u = 0; u < 6; ++u)
                h += vals[u] * *(const f32x4*)&sw1t[idx[u] * 32 + 4 * p];
        }
#pragma unroll
        for (int j = 0; j < 4; ++j) h[j] = fmaxf(h[j], 0.f);

        ushort* dst = (which ? qp : ip) + (size_t)m * CIN + 256;

        // layer 2 in two passes of 16 outputs (peak regs ~16 instead of 32)
        {
            float part[16];
#pragma unroll
            for (int c = 0; c < 16; ++c) {
                const f32x4 w4 = *(const f32x4*)&sw2[c * 32 + 4 * p];
                part[c] = (h[0] * w4[0] + h[1] * w4[1]) + (h[2] * w4[2] + h[3] * w4[3]);
            }
#pragma unroll
            for (int c = 0; c < 16; ++c) part[c] += __shfl_xor(part[c], 1);
#pragma unroll
            for (int c = 0; c < 16; ++c) part[c] += __shfl_xor(part[c], 2);
#pragma unroll
            for (int c = 0; c < 16; ++c) part[c] += __shfl_xor(part[c], 4);
            if (p < 4) {
                u16x4 w;
#pragma unroll
                for (int r = 0; r < 4; ++r) w[r] = f2bf(sb2[4 * p + r] + part[4 * p + r]);
                *(u16x4*)(dst + 4 * p) = w;
            }
        }
        {
            float part[16];
#pragma unroll
            for (int c = 0; c < 16; ++c) {
                const f32x4 w4 = *(const f32x4*)&sw2[(16 + c) * 32 + 4 * p];
                part[c] = (h[0] * w4[0] + h[1] * w4[1]) + (h[2] * w4[2] + h[3] * w4[3]);
            }
#pragma unroll
            for (int c = 0; c < 16; ++c) part[c] += __shfl_xor(part[c], 1);
#pragma unroll
            for (int c = 0; c < 16; ++c) part[c] += __shfl_xor(part[c], 2);
#pragma unroll
            for (int c = 0; c < 16; ++c) part[c] += __shfl_xor(part[c], 4);
            if (p >= 4) {
                const int pb = p - 4;
                u16x4 w;
#pragma unroll
                for (int r = 0; r < 4; ++r) w[r] = f2bf(sb2[16 + 4 * pb + r] + part[4 * pb + r]);
                *(u16x4*)(dst + 16 + 4 * pb) = w;
            }
        }
    } else if (blk < 1856) {
        // ---------------- cast_wo ----------------
        const int f = ((blk - 1792) * 256 + t) * 4;
        const float4 a = *(const float4*)(Wo + f);
        u16x4 o = {f2bf(a.x), f2bf(a.y), f2bf(a.z), f2bf(a.w)};
        *(u16x4*)(WoB + f) = o;
    } else {
        // ---------------- cast_x ----------------
        const int i = blk - 1856;
        const int which = i >> 11;
        const size_t f = ((size_t)(i & 2047) * 256 + t) * 8;
        const int row = (int)(f >> 8);
        const int col = (int)(f & 255);
        const float* src = which ? Qin : X;
        ushort* dst = which ? qp : ip;
        const float4 a = *(const float4*)(src + f);
        const float4 b = *(const float4*)(src + f + 4);
        u16x4 o0 = {f2bf(a.x), f2bf(a.y), f2bf(a.z), f2bf(a.w)};
        u16x4 o1 = {f2bf(b.x), f2bf(b.y), f2bf(b.z), f2bf(b.w)};
        *(u16x4*)(dst + (size_t)row * CIN + col) = o0;
        *(u16x4*)(dst + (size_t)row * CIN + col + 4) = o1;
    }
}

// ---------------------------------------------------------------------------
// Kernel 2: QKV projection -- counted-vmcnt pipeline (unchanged from r8).
// ---------------------------------------------------------------------------
__global__ __launch_bounds__(256) void qkv_mfma(
        const ushort* __restrict__ qp, const ushort* __restrict__ ip,
        const ushort* __restrict__ Wb, const float* __restrict__ bias,
        ushort* __restrict__ qout, ushort* __restrict__ kout, ushort* __restrict__ vout) {
    __shared__ ushort SA[3 * 6144];   // 3 x (A 8KB + B 4KB) = 36 KB
    const int wv = threadIdx.x >> 6, lane = threadIdx.x & 63;
    const int l16 = lane & 15, quad = lane >> 4;
    const int m0b = blockIdx.x * 128;
    const int y = blockIdx.y;
    const int mat = y >> 2;
    const int n0 = y * 64;
    const ushort* A = (mat == 0) ? qp : ip;

    size_t asrc[2];
    int adst[2];
#pragma unroll
    for (int i = 0; i < 2; ++i) {
        const int idx = wv * 128 + i * 64 + lane;
        const int row = idx >> 2;
        const int cc = (idx & 3) ^ ((row >> 1) & 3);
        asrc[i] = (size_t)(m0b + row) * CIN + cc * 8;
        adst[i] = (wv * 128 + i * 64) * 8;
    }
    const int bidx = wv * 64 + lane;
    const int brow = bidx >> 2;
    const int bcc = (bidx & 3) ^ ((brow >> 1) & 3);
    const size_t bsrc = (size_t)(n0 + brow) * CIN + bcc * 8;
    const int bdst = 4096 + wv * 512;

    const int rsw = quad ^ ((l16 >> 1) & 3);
    int aoff[2];
#pragma unroll
    for (int s = 0; s < 2; ++s)
        aoff[s] = ((32 * wv + 16 * s + l16) * 4 + rsw) * 8;
    int boff[4];
#pragma unroll
    for (int c = 0; c < 4; ++c)
        boff[c] = 4096 + ((16 * c + l16) * 4 + rsw) * 8;

    f32x4 acc[2][4];
#pragma unroll
    for (int s = 0; s < 2; ++s)
#pragma unroll
        for (int c = 0; c < 4; ++c) acc[s][c] = (f32x4){0.f, 0.f, 0.f, 0.f};

#pragma unroll
    for (int pt = 0; pt < 2; ++pt) {
        ushort* db = SA + pt * 6144;
        gload_lds16(A + asrc[0] + pt * 32, db + adst[0]);
        gload_lds16(A + asrc[1] + pt * 32, db + adst[1]);
        gload_lds16(Wb + bsrc + pt * 32, db + bdst);
    }

    int co = 0, po = 12288;
    for (int t = 0; t < 9; ++t) {
        if (t < 8) asm volatile("s_waitcnt vmcnt(3)" ::: "memory");
        else       asm volatile("s_waitcnt vmcnt(0)" ::: "memory");
        __builtin_amdgcn_s_barrier();

        if (t + 2 < 9) {
            ushort* db = SA + po;
            gload_lds16(A + asrc[0] + (t + 2) * 32, db + adst[0]);
            gload_lds16(A + asrc[1] + (t + 2) * 32, db + adst[1]);
            gload_lds16(Wb + bsrc + (t + 2) * 32, db + bdst);
            po = (po == 12288) ? 0 : po + 6144;
        }
        const ushort* buf = SA + co;
        co = (co == 12288) ? 0 : co + 6144;

        bf16x8 af[2], bf[4];
#pragma unroll
        for (int s = 0; s < 2; ++s)
            af[s] = *(const bf16x8*)(buf + aoff[s]);
#pragma unroll
        for (int c = 0; c < 4; ++c)
            bf[c] = *(const bf16x8*)(buf + boff[c]);
        if (mat < 2) {
#pragma unroll
            for (int s = 0; s < 2; ++s)
#pragma unroll
                for (int c = 0; c < 4; ++c)
                    acc[s][c] = __builtin_amdgcn_mfma_f32_16x16x32_bf16(bf[c], af[s], acc[s][c], 0, 0, 0);
        } else {
#pragma unroll
            for (int s = 0; s < 2; ++s)
#pragma unroll
                for (int c = 0; c < 4; ++c)
                    acc[s][c] = __builtin_amdgcn_mfma_f32_16x16x32_bf16(af[s], bf[c], acc[s][c], 0, 0, 0);
        }
    }

    const int h = y & 3;
    const int m0 = m0b + wv * 32;
    if (mat < 2) {
        const float scale = (mat == 0) ? (0.125f * 1.44269504088896f) : 1.0f;
        ushort* out = (mat == 0) ? qout : kout;
#pragma unroll
        for (int s = 0; s < 2; ++s) {
            const int tokm = m0 + 16 * s + l16;
            const int b = tokm >> 11, nn = tokm & (NSEQ - 1);
#pragma unroll
            for (int c = 0; c < 4; ++c) {
                const f32x4 b4 = *(const f32x4*)&bias[n0 + 16 * c + quad * 4];
                u16x4 w;
#pragma unroll
                for (int r = 0; r < 4; ++r) w[r] = f2bf((acc[s][c][r] + b4[r]) * scale);
                *(u16x4*)(out + ((size_t)(b * NH + h) * NSEQ + nn) * DHD + 16 * c + quad * 4) = w;
            }
        }
    } else {
#pragma unroll
        for (int s = 0; s < 2; ++s) {
            const int tok0 = m0 + 16 * s + quad * 4;
            const int b = tok0 >> 11, nn0 = tok0 & (NSEQ - 1);
#pragma unroll
            for (int c = 0; c < 4; ++c) {
                const int d = 16 * c + l16;
                const float bv = bias[n0 + d];
                u16x4 w;
#pragma unroll
                for (int r = 0; r < 4; ++r) w[r] = f2bf(acc[s][c][r] + bv);
                *(u16x4*)(vout + ((size_t)(b * NH + h) * DHD + d) * NSEQ + nn0) = w;
            }
        }
    }
}

// ---------------------------------------------------------------------------
// Kernel 3: MFMA flash attention -- DEPTH-3 + ones-MFMA row-sum + setprio.
// Changes vs r10 (each proven separately):
//  * 4 staging buffers per key-group (64KB LDS total, still 2 blocks/CU);
//    prologue stages 3 tiles; steady-state wait vmcnt(4) keeps tiles t+1,t+2
//    in flight ACROSS the barrier (r2: deeper pipeline helped this loop).
//  * Softmax denominator on the MATRIX pipe: Lc[s] = mfma(ones, P, Lc[s])
//    -> every acc reg = full 32-key row sum for query col l16 (r1/r2
//    verified, same absmax). Kills 14 VALU adds/tile + 2 epilogue shuffles.
//  * s_setprio(1) around MFMA clusters (T5: pays on phase-split attn waves).
// ---------------------------------------------------------------------------
__global__ __launch_bounds__(512, 4) void attn_kernel(
        const ushort* __restrict__ q, const ushort* __restrict__ k,
        const ushort* __restrict__ v, ushort* __restrict__ out) {
    __shared__ ushort SL[32768];   // 2 groups x 4 buf x 8 KB = 64 KB
    const int bh = blockIdx.y;
    const int wv = threadIdx.x >> 6;     // 0..7
    const int grp = wv >> 2;             // key half
    const int wq = wv & 3;               // q sub-block within group
    const int lane = threadIdx.x & 63;
    const int l16 = lane & 15, quad = lane >> 4;
    const int q0 = blockIdx.x * 128 + wq * 32;

    const ushort* qb = q + (size_t)bh * NSEQ * DHD;
    const ushort* kb = k + (size_t)bh * NSEQ * DHD + (size_t)(grp * 1024) * DHD;
    const ushort* vb = v + (size_t)bh * DHD * NSEQ + grp * 1024;
    ushort* SG = SL + grp * 16384;       // per-group staging base (ushorts)

    bf16x8 qf[2][2];
#pragma unroll
    for (int s = 0; s < 2; ++s)
#pragma unroll
        for (int hh = 0; hh < 2; ++hh)
            qf[s][hh] = *(const bf16x8*)(qb + (size_t)(q0 + 16 * s + l16) * DHD + 32 * hh + quad * 8);

    const int krow_s = 8 * wq + (lane >> 3);
    const int kcg = (lane & 7) ^ sw(krow_s);
    const size_t ksrc = (size_t)krow_s * DHD + kcg * 8;
    const int kdst = wq * 512;
    const int vrow_s = 16 * wq + (lane >> 2);
    const int vcg = (lane & 3) ^ swv(vrow_s);
    const size_t vsrc = (size_t)vrow_s * NSEQ + vcg * 8;
    const int vdst = wq * 512;

    const int krow = 8 * (l16 >> 2) + (l16 & 3);
    int koff[2][2];
    int voff[4];
#pragma unroll
    for (int m = 0; m < 2; ++m) {
        const int row = krow + 4 * m;
#pragma unroll
        for (int hh = 0; hh < 2; ++hh)
            koff[m][hh] = row * 64 + (((hh * 4 + quad) ^ sw(row))) * 8;
    }
#pragma unroll
    for (int c = 0; c < 4; ++c) {
        const int d = 16 * c + l16;
        voff[c] = 2048 + d * 32 + ((quad ^ swv(d))) * 8;
    }

    f32x4 Oc[2][4];
#pragma unroll
    for (int s = 0; s < 2; ++s)
#pragma unroll
        for (int c = 0; c < 4; ++c) Oc[s][c] = (f32x4){0.f, 0.f, 0.f, 0.f};
    f32x4 Lc[2];
#pragma unroll
    for (int s = 0; s < 2; ++s) Lc[s] = (f32x4){0.f, 0.f, 0.f, 0.f};
    const short ob = (short)0x3F80;                         // bf16 1.0
    const bf16x8 onesf = {ob, ob, ob, ob, ob, ob, ob, ob};

    // prologue: stage tiles 0,1,2 (6 loads in flight)
#pragma unroll
    for (int pt = 0; pt < 3; ++pt) {
        ushort* db = SG + pt * 4096;
        gload_lds16(kb + (size_t)(pt * 32) * DHD + ksrc, db + kdst);
        gload_lds16(vb + pt * 32 + vsrc, db + 2048 + vdst);
    }

    for (int t = 0; t < 32; ++t) {
        // retire OWN tile-t loads; tiles t+1,t+2 stay in flight across barrier
        if (t < 30)       asm volatile("s_waitcnt vmcnt(4)" ::: "memory");
        else if (t == 30) asm volatile("s_waitcnt vmcnt(2)" ::: "memory");
        else              asm volatile("s_waitcnt vmcnt(0)" ::: "memory");
        __builtin_amdgcn_s_barrier();

        if (t + 3 < 32) {   // stage tile t+3 into buf freed at t-1
            ushort* db = SG + ((t + 3) & 3) * 4096;
            gload_lds16(kb + (size_t)((t + 3) * 32) * DHD + ksrc, db + kdst);
            gload_lds16(vb + (t + 3) * 32 + vsrc, db + 2048 + vdst);
        }
        const ushort* buf = SG + (t & 3) * 4096;

        bf16x8 kf[2][2], vf[4];
#pragma unroll
        for (int m = 0; m < 2; ++m)
#pragma unroll
            for (int hh = 0; hh < 2; ++hh)
                kf[m][hh] = *(const bf16x8*)(buf + koff[m][hh]);
#pragma unroll
        for (int c = 0; c < 4; ++c)
            vf[c] = *(const bf16x8*)(buf + voff[c]);

#pragma unroll
        for (int s = 0; s < 2; ++s) {
            f32x4 s0 = (f32x4){0.f, 0.f, 0.f, 0.f};
            f32x4 s1 = (f32x4){0.f, 0.f, 0.f, 0.f};
            __builtin_amdgcn_s_setprio(1);
            s0 = __builtin_amdgcn_mfma_f32_16x16x32_bf16(kf[0][0], qf[s][0], s0, 0, 0, 0);
            s0 = __builtin_amdgcn_mfma_f32_16x16x32_bf16(kf[0][1], qf[s][1], s0, 0, 0, 0);
            s1 = __builtin_amdgcn_mfma_f32_16x16x32_bf16(kf[1][0], qf[s][0], s1, 0, 0, 0);
            s1 = __builtin_amdgcn_mfma_f32_16x16x32_bf16(kf[1][1], qf[s][1], s1, 0, 0, 0);
            __builtin_amdgcn_s_setprio(0);
            // s includes log2(e) (folded into q): p = exp2(s)

            float p0[4], p1[4];
#pragma unroll
            for (int r = 0; r < 4; ++r) {
                p0[r] = fast_exp2(s0[r]);
                p1[r] = fast_exp2(s1[r]);
            }

            union { bf16x8 v8; unsigned d[4]; } P;
            P.d[0] = pack_bf_trunc(p0[0], p0[1]);
            P.d[1] = pack_bf_trunc(p0[2], p0[3]);
            P.d[2] = pack_bf_trunc(p1[0], p1[1]);
            P.d[3] = pack_bf_trunc(p1[2], p1[3]);
            __builtin_amdgcn_s_setprio(1);
            // row-sum on the matrix pipe: every output reg = sum_k P[k][q]
            Lc[s] = __builtin_amdgcn_mfma_f32_16x16x32_bf16(onesf, P.v8, Lc[s], 0, 0, 0);
#pragma unroll
            for (int c = 0; c < 4; ++c)
                Oc[s][c] = __builtin_amdgcn_mfma_f32_16x16x32_bf16(vf[c], P.v8, Oc[s][c], 0, 0, 0);
            __builtin_amdgcn_s_setprio(0);
        }
    }

    // combine the two key-halves in LDS (reuse staging memory).
    // Lc[s][0] already holds this group's full 1024-key denominator for
    // query col l16 (identical across quads/regs) -- no shuffles needed.
    __syncthreads();
    float* exch = (float*)SL;                 // [128 q][68 pad] f32 = 34816 B
    float* lx   = ((float*)SL) + 128 * 68;    // 128 f32
    if (grp == 1) {
#pragma unroll
        for (int s = 0; s < 2; ++s) {
            const int lq = wq * 32 + 16 * s + l16;
#pragma unroll
            for (int c = 0; c < 4; ++c)
                *(f32x4*)&exch[lq * 68 + 16 * c + 4 * quad] = Oc[s][c];
            if (quad == 0) lx[lq] = Lc[s][0];
        }
    }
    __syncthreads();
    if (grp == 0) {
        const int b = bh >> 2, h = bh & 3;
#pragma unroll
        for (int s = 0; s < 2; ++s) {
            const int lq = wq * 32 + 16 * s + l16;
            const float linv = 1.0f / (Lc[s][0] + lx[lq]);
            ushort* dst = out + (size_t)(b * NSEQ + blockIdx.x * 128 + lq) * HID + h * DHD;
#pragma unroll
            for (int c = 0; c < 4; ++c) {
                const f32x4 o1 = *(const f32x4*)&exch[lq * 68 + 16 * c + 4 * quad];
                u16x4 w;
#pragma unroll
                for (int r = 0; r < 4; ++r) w[r] = f2bf((Oc[s][c][r] + o1[r]) * linv);
                *(u16x4*)(dst + 16 * c + quad * 4) = w;
            }
        }
    }
}

// ---------------------------------------------------------------------------
// Kernel 4: out_proj + bias + residual + LayerNorm (unchanged from r8).
// ---------------------------------------------------------------------------
__global__ __launch_bounds__(256) void oproj_ln_mfma(
        const ushort* __restrict__ abuf, const float* __restrict__ Qin,
        const ushort* __restrict__ WoB, const float* __restrict__ bo,
        const float* __restrict__ g, const float* __restrict__ be,
        float* __restrict__ out) {
    __shared__ float yt[16][260];
    const int wv = threadIdx.x >> 6, lane = threadIdx.x & 63;
    const int l16 = lane & 15, quad = lane >> 4;
    const int m0 = blockIdx.x * 16;
    const int n0 = wv * 64;

    f32x4 acc[4];
#pragma unroll
    for (int c = 0; c < 4; ++c) acc[c] = (f32x4){0.f, 0.f, 0.f, 0.f};

    for (int kk = 0; kk < HID; kk += 32) {
        const bf16x8 af = *(const bf16x8*)(abuf + (size_t)(m0 + l16) * HID + kk + quad * 8);
        bf16x8 bf[4];
#pragma unroll
        for (int c = 0; c < 4; ++c)
            bf[c] = *(const bf16x8*)(WoB + (size_t)(n0 + 16 * c + l16) * HID + kk + quad * 8);
#pragma unroll
        for (int c = 0; c < 4; ++c)
            acc[c] = __builtin_amdgcn_mfma_f32_16x16x32_bf16(af, bf[c], acc[c], 0, 0, 0);
    }

#pragma unroll
    for (int c = 0; c < 4; ++c) {
        const int col = n0 + 16 * c + l16;
        const float bv = bo[col];
#pragma unroll
        for (int r = 0; r < 4; ++r) {
            const int row = quad * 4 + r;
            yt[row][col] = acc[c][r] + bv + Qin[(size_t)(m0 + row) * HID + col];
        }
    }
    __syncthreads();

    float gv[4], bev[4];
#pragma unroll
    for (int u = 0; u < 4; ++u) { gv[u] = g[lane + 64 * u]; bev[u] = be[lane + 64 * u]; }

    for (int rr = 0; rr < 4; ++rr) {
        const int row = wv * 4 + rr;
        float sm = 0.f, ssq = 0.f;
        float yv[4];
#pragma unroll
        for (int u = 0; u < 4; ++u) {
            yv[u] = yt[row][lane + 64 * u];
            sm += yv[u]; ssq += yv[u] * yv[u];
        }
#pragma unroll
        for (int off = 32; off >= 1; off >>= 1) {
            sm += __shfl_xor(sm, off);
            ssq += __shfl_xor(ssq, off);
        }
        const float mu = sm * (1.f / 256.f);
        const float rs = rsqrtf(fmaxf(ssq * (1.f / 256.f) - mu * mu, 0.f) + 1e-5f);
        float* dst = out + (size_t)(m0 + row) * HID;
#pragma unroll
        for (int u = 0; u < 4; ++u)
            dst[lane + 64 * u] = (yv[u] - mu) * rs * gv[u] + bev[u];
    }
}

// ---------------------------------------------------------------------------
extern "C" void kernel_launch(void* const* d_in, const int* in_sizes, int n_in,
                              void* d_out, int out_size, void* d_ws, size_t ws_size,
                              hipStream_t stream) {
    const float* inputs       = (const float*)d_in[0];
    const float* Q_in         = (const float*)d_in[1];
    const float* input_coords = (const float*)d_in[2];
    const float* Q_in_coords  = (const float*)d_in[3];
    const float* Wq           = (const float*)d_in[4];
    const float* Wk           = (const float*)d_in[5];
    const float* Wv           = (const float*)d_in[6];
    const float* in_proj_w    = (const float*)d_in[7];
    const float* in_proj_b    = (const float*)d_in[8];
    const float* out_proj_w   = (const float*)d_in[9];
    const float* out_proj_b   = (const float*)d_in[10];
    const float* ln_g         = (const float*)d_in[11];
    const float* ln_b         = (const float*)d_in[12];
    const float* pe_w1        = (const float*)d_in[13];
    const float* pe_b1        = (const float*)d_in[14];
    const float* pe_w2        = (const float*)d_in[15];
    const float* pe_b2        = (const float*)d_in[16];

    char* ws = (char*)d_ws;
    ushort* Wb   = (ushort*)(ws);              // 768*288*2     = 442368
    ushort* WoB  = (ushort*)(ws + 442368);     // 256*256*2     = 131072
    ushort* qp   = (ushort*)(ws + 573440);     // 16384*288*2   = 9437184
    ushort* ip   = (ushort*)(ws + 10010624);   // 9437184
    ushort* qbuf = (ushort*)(ws + 19447808);   // 8388608
    ushort* kbuf = (ushort*)(ws + 27836416);   // 8388608
    ushort* vbuf = (ushort*)(ws + 36225024);   // 8388608 (transposed [bh][64][n])
    ushort* abuf = (ushort*)(ws + 44613632);   // 8388608 -> end 53002240 bytes

    prep_kernel<<<5952, 256, 0, stream>>>(input_coords, Q_in_coords,
                                          pe_w1, pe_b1, pe_w2, pe_b2,
                                          inputs, Q_in, in_proj_w,
                                          Wq, Wk, Wv, out_proj_w,
                                          ip, qp, Wb, WoB);
    qkv_mfma<<<dim3(128, 12), 256, 0, stream>>>(qp, ip, Wb, in_proj_b,
                                                qbuf, kbuf, vbuf);
    attn_kernel<<<dim3(16, 32), 512, 0, stream>>>(qbuf, kbuf, vbuf, abuf);
    oproj_ln_mfma<<<1024, 256, 0, stream>>>(abuf, Q_in, WoB, out_proj_b,
                                            ln_g, ln_b, (float*)d_out);
}

// Round 12
// 212.947 us; speedup vs baseline: 1.0567x; 1.0070x over previous
//
#include <hip/hip_runtime.h>
#include <math.h>

#define HID 256
#define CIN 288      // HID + POS
#define NTOK 16384   // B*N
#define NSEQ 2048
#define NH 4
#define DHD 64
#define TWO_PI 6.2831853071795864769f

typedef __attribute__((ext_vector_type(8))) short bf16x8;
typedef __attribute__((ext_vector_type(4))) float f32x4;
typedef __attribute__((ext_vector_type(4))) unsigned short u16x4;

__device__ __forceinline__ ushort f2bf(float x) {
    unsigned u = __float_as_uint(x);
    u = (u + 0x7FFFu + ((u >> 16) & 1u)) >> 16;
    return (ushort)u;
}

__device__ __forceinline__ float fast_exp2(float x) {
    return __builtin_amdgcn_exp2f(x);   // v_exp_f32
}

// pack two fp32 -> one dword of truncated bf16 (lo=a, hi=b) via v_perm_b32
__device__ __forceinline__ unsigned pack_bf_trunc(float a, float b) {
    return __builtin_amdgcn_perm(__float_as_uint(b), __float_as_uint(a), 0x07060302u);
}

// async global->LDS, 16 B per lane: LDS dst = base + lane*16 (wave-uniform base)
__device__ __forceinline__ void gload_lds16(const ushort* g, ushort* l) {
    __builtin_amdgcn_global_load_lds(
        (const __attribute__((address_space(1))) unsigned*)g,
        (__attribute__((address_space(3))) unsigned*)l, 16, 0, 0);
}

// LDS chunk swizzle for 128B rows (8 x 16B chunks/row): uniform bank classes
__device__ __forceinline__ int sw(int row) {
    return (((row >> 3) << 1) ^ row) & 7;
}

// chunk swizzle for 64B rows (4 x 16B chunks/row)
__device__ __forceinline__ int swv(int row) {
    return ((row & 3) ^ ((row >> 2) & 3));
}

// ---------------------------------------------------------------------------
// Kernel 1 (MERGED PREP): fuse_w | pos_mlp | cast_wo | cast_x (unchanged from
// round 9 -- launch_bounds(256,8) occupancy fix; VGPR<=64, no spill).
// ---------------------------------------------------------------------------
__global__ __launch_bounds__(256, 8) void prep_kernel(
        const float* __restrict__ icoords, const float* __restrict__ qcoords,
        const float* __restrict__ w1, const float* __restrict__ b1,
        const float* __restrict__ w2, const float* __restrict__ b2,
        const float* __restrict__ X, const float* __restrict__ Qin,
        const float* __restrict__ inW,
        const float* __restrict__ Wq, const float* __restrict__ Wk,
        const float* __restrict__ Wv,
        const float* __restrict__ Wo,
        ushort* __restrict__ ip, ushort* __restrict__ qp,
        ushort* __restrict__ Wb, ushort* __restrict__ WoB) {
    __shared__ float SMEM[4160];
    const int blk = blockIdx.x;
    const int t = threadIdx.x;

    if (blk < 768) {
        // ---------------- fuse_w ----------------
        float* wrow = SMEM;
        const int o = blk & 255;
        const int mat = blk >> 8;
        wrow[t] = inW[(mat * 256 + o) * 256 + t];
        __syncthreads();
        const float* Wm = (mat == 0) ? Wq : ((mat == 1) ? Wk : Wv);
        const int t2 = 256 + (t & 31);
        float acc0 = 0.f, acc1 = 0.f;
#pragma unroll 16
        for (int h = 0; h < 256; ++h) {
            const float wh = wrow[h];
            acc0 += wh * Wm[h * CIN + t];
            acc1 += wh * Wm[h * CIN + t2];
        }
        ushort* dst = Wb + (size_t)(mat * 256 + o) * CIN;
        dst[t] = f2bf(acc0);
        if (t < 32) dst[t2] = f2bf(acc1);
    } else if (blk < 1792) {
        // ---------------- pos_mlp (8 threads per token) ----------------
        float* sw1t = SMEM;            // [96][32] transposed
        float* sb1  = SMEM + 3072;     // [32]
        float* sw2  = SMEM + 3104;     // [32][32]
        float* sb2  = SMEM + 4128;     // [32]
        for (int i = t; i < 96 * 32; i += 256) {
            const int e = i >> 5, r = i & 31;
            sw1t[i] = w1[r * 96 + e];
        }
        for (int i = t; i < 32 * 32; i += 256) sw2[i] = w2[i];
        if (t < 32) { sb1[t] = b1[t]; sb2[t] = b2[t]; }
        __syncthreads();

        const int p = t & 7;                       // owns h rows 4p..4p+3
        const int tok = (blk - 768) * 32 + (t >> 3);
        const int which = tok >> 14;
        const int m = tok & (NTOK - 1);
        const float* cr = (which ? qcoords : icoords) + m * 4;
        const float x = cr[1] * TWO_PI;
        const float y = cr[2] * TWO_PI;
        const float z = cr[3] * TWO_PI;

        f32x4 h = *(const f32x4*)&sb1[4 * p];

        for (int jj = 0; jj < 16; ++jj) {
            const float inv = 1.0f / (1.0f + 0.0625f * (float)jj);
            const float xs = x * inv, ys = y * inv, zs = z * inv;
            const float cx = __cosf(xs);
            float vals[6];
            int idx[6];
            vals[0] = __sinf(ys);  idx[0] = 2 * jj;
            vals[1] = __cosf(ys);  idx[1] = 2 * jj + 1;
            vals[2] = __sinf(xs);  idx[2] = 32 + 2 * jj;
            vals[3] = cx;          idx[3] = 32 + 2 * jj + 1;
            vals[4] = __sinf(zs);  idx[4] = 64 + 2 * jj;
            vals[5] = cx;          idx[5] = 64 + 2 * jj + 1;   // reference bug: cos of x
#pragma unroll
            for (int u = 0; u < 6; ++u)
                h += vals[u] * *(const f32x4*)&sw1t[idx[u] * 32 + 4 * p];
        }
#pragma unroll
        for (int j = 0; j < 4; ++j) h[j] = fmaxf(h[j], 0.f);

        ushort* dst = (which ? qp : ip) + (size_t)m * CIN + 256;

        // layer 2 in two passes of 16 outputs (peak regs ~16 instead of 32)
        {
            float part[16];
#pragma unroll
            for (int c = 0; c < 16; ++c) {
                const f32x4 w4 = *(const f32x4*)&sw2[c * 32 + 4 * p];
                part[c] = (h[0] * w4[0] + h[1] * w4[1]) + (h[2] * w4[2] + h[3] * w4[3]);
            }
#pragma unroll
            for (int c = 0; c < 16; ++c) part[c] += __shfl_xor(part[c], 1);
#pragma unroll
            for (int c = 0; c < 16; ++c) part[c] += __shfl_xor(part[c], 2);
#pragma unroll
            for (int c = 0; c < 16; ++c) part[c] += __shfl_xor(part[c], 4);
            if (p < 4) {
                u16x4 w;
#pragma unroll
                for (int r = 0; r < 4; ++r) w[r] = f2bf(sb2[4 * p + r] + part[4 * p + r]);
                *(u16x4*)(dst + 4 * p) = w;
            }
        }
        {
            float part[16];
#pragma unroll
            for (int c = 0; c < 16; ++c) {
                const f32x4 w4 = *(const f32x4*)&sw2[(16 + c) * 32 + 4 * p];
                part[c] = (h[0] * w4[0] + h[1] * w4[1]) + (h[2] * w4[2] + h[3] * w4[3]);
            }
#pragma unroll
            for (int c = 0; c < 16; ++c) part[c] += __shfl_xor(part[c], 1);
#pragma unroll
            for (int c = 0; c < 16; ++c) part[c] += __shfl_xor(part[c], 2);
#pragma unroll
            for (int c = 0; c < 16; ++c) part[c] += __shfl_xor(part[c], 4);
            if (p >= 4) {
                const int pb = p - 4;
                u16x4 w;
#pragma unroll
                for (int r = 0; r < 4; ++r) w[r] = f2bf(sb2[16 + 4 * pb + r] + part[4 * pb + r]);
                *(u16x4*)(dst + 16 + 4 * pb) = w;
            }
        }
    } else if (blk < 1856) {
        // ---------------- cast_wo ----------------
        const int f = ((blk - 1792) * 256 + t) * 4;
        const float4 a = *(const float4*)(Wo + f);
        u16x4 o = {f2bf(a.x), f2bf(a.y), f2bf(a.z), f2bf(a.w)};
        *(u16x4*)(WoB + f) = o;
    } else {
        // ---------------- cast_x ----------------
        const int i = blk - 1856;
        const int which = i >> 11;
        const size_t f = ((size_t)(i & 2047) * 256 + t) * 8;
        const int row = (int)(f >> 8);
        const int col = (int)(f & 255);
        const float* src = which ? Qin : X;
        ushort* dst = which ? qp : ip;
        const float4 a = *(const float4*)(src + f);
        const float4 b = *(const float4*)(src + f + 4);
        u16x4 o0 = {f2bf(a.x), f2bf(a.y), f2bf(a.z), f2bf(a.w)};
        u16x4 o1 = {f2bf(b.x), f2bf(b.y), f2bf(b.z), f2bf(b.w)};
        *(u16x4*)(dst + (size_t)row * CIN + col) = o0;
        *(u16x4*)(dst + (size_t)row * CIN + col + 4) = o1;
    }
}

// ---------------------------------------------------------------------------
// Kernel 2: QKV projection -- counted-vmcnt pipeline (unchanged from r8).
// (A-tile reuse runs along blockIdx.y, which preserves dispatch%8 -> already
// XCD-local; no swizzle needed here.)
// ---------------------------------------------------------------------------
__global__ __launch_bounds__(256) void qkv_mfma(
        const ushort* __restrict__ qp, const ushort* __restrict__ ip,
        const ushort* __restrict__ Wb, const float* __restrict__ bias,
        ushort* __restrict__ qout, ushort* __restrict__ kout, ushort* __restrict__ vout) {
    __shared__ ushort SA[3 * 6144];   // 3 x (A 8KB + B 4KB) = 36 KB
    const int wv = threadIdx.x >> 6, lane = threadIdx.x & 63;
    const int l16 = lane & 15, quad = lane >> 4;
    const int m0b = blockIdx.x * 128;
    const int y = blockIdx.y;
    const int mat = y >> 2;
    const int n0 = y * 64;
    const ushort* A = (mat == 0) ? qp : ip;

    size_t asrc[2];
    int adst[2];
#pragma unroll
    for (int i = 0; i < 2; ++i) {
        const int idx = wv * 128 + i * 64 + lane;
        const int row = idx >> 2;
        const int cc = (idx & 3) ^ ((row >> 1) & 3);
        asrc[i] = (size_t)(m0b + row) * CIN + cc * 8;
        adst[i] = (wv * 128 + i * 64) * 8;
    }
    const int bidx = wv * 64 + lane;
    const int brow = bidx >> 2;
    const int bcc = (bidx & 3) ^ ((brow >> 1) & 3);
    const size_t bsrc = (size_t)(n0 + brow) * CIN + bcc * 8;
    const int bdst = 4096 + wv * 512;

    const int rsw = quad ^ ((l16 >> 1) & 3);
    int aoff[2];
#pragma unroll
    for (int s = 0; s < 2; ++s)
        aoff[s] = ((32 * wv + 16 * s + l16) * 4 + rsw) * 8;
    int boff[4];
#pragma unroll
    for (int c = 0; c < 4; ++c)
        boff[c] = 4096 + ((16 * c + l16) * 4 + rsw) * 8;

    f32x4 acc[2][4];
#pragma unroll
    for (int s = 0; s < 2; ++s)
#pragma unroll
        for (int c = 0; c < 4; ++c) acc[s][c] = (f32x4){0.f, 0.f, 0.f, 0.f};

#pragma unroll
    for (int pt = 0; pt < 2; ++pt) {
        ushort* db = SA + pt * 6144;
        gload_lds16(A + asrc[0] + pt * 32, db + adst[0]);
        gload_lds16(A + asrc[1] + pt * 32, db + adst[1]);
        gload_lds16(Wb + bsrc + pt * 32, db + bdst);
    }

    int co = 0, po = 12288;
    for (int t = 0; t < 9; ++t) {
        if (t < 8) asm volatile("s_waitcnt vmcnt(3)" ::: "memory");
        else       asm volatile("s_waitcnt vmcnt(0)" ::: "memory");
        __builtin_amdgcn_s_barrier();

        if (t + 2 < 9) {
            ushort* db = SA + po;
            gload_lds16(A + asrc[0] + (t + 2) * 32, db + adst[0]);
            gload_lds16(A + asrc[1] + (t + 2) * 32, db + adst[1]);
            gload_lds16(Wb + bsrc + (t + 2) * 32, db + bdst);
            po = (po == 12288) ? 0 : po + 6144;
        }
        const ushort* buf = SA + co;
        co = (co == 12288) ? 0 : co + 6144;

        bf16x8 af[2], bf[4];
#pragma unroll
        for (int s = 0; s < 2; ++s)
            af[s] = *(const bf16x8*)(buf + aoff[s]);
#pragma unroll
        for (int c = 0; c < 4; ++c)
            bf[c] = *(const bf16x8*)(buf + boff[c]);
        if (mat < 2) {
#pragma unroll
            for (int s = 0; s < 2; ++s)
#pragma unroll
                for (int c = 0; c < 4; ++c)
                    acc[s][c] = __builtin_amdgcn_mfma_f32_16x16x32_bf16(bf[c], af[s], acc[s][c], 0, 0, 0);
        } else {
#pragma unroll
            for (int s = 0; s < 2; ++s)
#pragma unroll
                for (int c = 0; c < 4; ++c)
                    acc[s][c] = __builtin_amdgcn_mfma_f32_16x16x32_bf16(af[s], bf[c], acc[s][c], 0, 0, 0);
        }
    }

    const int h = y & 3;
    const int m0 = m0b + wv * 32;
    if (mat < 2) {
        const float scale = (mat == 0) ? (0.125f * 1.44269504088896f) : 1.0f;
        ushort* out = (mat == 0) ? qout : kout;
#pragma unroll
        for (int s = 0; s < 2; ++s) {
            const int tokm = m0 + 16 * s + l16;
            const int b = tokm >> 11, nn = tokm & (NSEQ - 1);
#pragma unroll
            for (int c = 0; c < 4; ++c) {
                const f32x4 b4 = *(const f32x4*)&bias[n0 + 16 * c + quad * 4];
                u16x4 w;
#pragma unroll
                for (int r = 0; r < 4; ++r) w[r] = f2bf((acc[s][c][r] + b4[r]) * scale);
                *(u16x4*)(out + ((size_t)(b * NH + h) * NSEQ + nn) * DHD + 16 * c + quad * 4) = w;
            }
        }
    } else {
#pragma unroll
        for (int s = 0; s < 2; ++s) {
            const int tok0 = m0 + 16 * s + quad * 4;
            const int b = tok0 >> 11, nn0 = tok0 & (NSEQ - 1);
#pragma unroll
            for (int c = 0; c < 4; ++c) {
                const int d = 16 * c + l16;
                const float bv = bias[n0 + d];
                u16x4 w;
#pragma unroll
                for (int r = 0; r < 4; ++r) w[r] = f2bf(acc[s][c][r] + bv);
                *(u16x4*)(vout + ((size_t)(b * NH + h) * DHD + d) * NSEQ + nn0) = w;
            }
        }
    }
}

// ---------------------------------------------------------------------------
// Kernel 3: MFMA flash attention (r11 structure) + XCD-AWARE WORK SWIZZLE.
// Default dispatch (x-fastest) spreads the 16 q-blocks sharing one bh's
// 512KB K/V panel round-robin over all 8 XCDs -> each private L2 fetches the
// same panel (FETCH 69.7MB vs ~34MB ideal, r7 profile). Remap so each XCD
// owns 4 whole bh's: d = y*16+x; xcd = d&7; bh = 4*xcd + (d>>3)/16;
// qx = (d>>3)&15. Bijective (512 = 8*64). Pure work permutation -- results
// identical. If the dispatch-order assumption is wrong, it's still a valid
// permutation (only FETCH_SIZE tells us whether locality improved).
// ---------------------------------------------------------------------------
__global__ __launch_bounds__(512, 4) void attn_kernel(
        const ushort* __restrict__ q, const ushort* __restrict__ k,
        const ushort* __restrict__ v, ushort* __restrict__ out) {
    __shared__ ushort SL[32768];   // 2 groups x 4 buf x 8 KB = 64 KB
    // XCD-aware (bh, qx) from dispatch-linear block id:
    const int lin = blockIdx.y * 16 + blockIdx.x;
    const int xcd = lin & 7;
    const int sub = lin >> 3;            // 0..63
    const int bh = (xcd << 2) | (sub >> 4);
    const int qx = sub & 15;

    const int wv = threadIdx.x >> 6;     // 0..7
    const int grp = wv >> 2;             // key half
    const int wq = wv & 3;               // q sub-block within group
    const int lane = threadIdx.x & 63;
    const int l16 = lane & 15, quad = lane >> 4;
    const int q0 = qx * 128 + wq * 32;

    const ushort* qb = q + (size_t)bh * NSEQ * DHD;
    const ushort* kb = k + (size_t)bh * NSEQ * DHD + (size_t)(grp * 1024) * DHD;
    const ushort* vb = v + (size_t)bh * DHD * NSEQ + grp * 1024;
    ushort* SG = SL + grp * 16384;       // per-group staging base (ushorts)

    bf16x8 qf[2][2];
#pragma unroll
    for (int s = 0; s < 2; ++s)
#pragma unroll
        for (int hh = 0; hh < 2; ++hh)
            qf[s][hh] = *(const bf16x8*)(qb + (size_t)(q0 + 16 * s + l16) * DHD + 32 * hh + quad * 8);

    const int krow_s = 8 * wq + (lane >> 3);
    const int kcg = (lane & 7) ^ sw(krow_s);
    const size_t ksrc = (size_t)krow_s * DHD + kcg * 8;
    const int kdst = wq * 512;
    const int vrow_s = 16 * wq + (lane >> 2);
    const int vcg = (lane & 3) ^ swv(vrow_s);
    const size_t vsrc = (size_t)vrow_s * NSEQ + vcg * 8;
    const int vdst = wq * 512;

    const int krow = 8 * (l16 >> 2) + (l16 & 3);
    int koff[2][2];
    int voff[4];
#pragma unroll
    for (int m = 0; m < 2; ++m) {
        const int row = krow + 4 * m;
#pragma unroll
        for (int hh = 0; hh < 2; ++hh)
            koff[m][hh] = row * 64 + (((hh * 4 + quad) ^ sw(row))) * 8;
    }
#pragma unroll
    for (int c = 0; c < 4; ++c) {
        const int d = 16 * c + l16;
        voff[c] = 2048 + d * 32 + ((quad ^ swv(d))) * 8;
    }

    f32x4 Oc[2][4];
#pragma unroll
    for (int s = 0; s < 2; ++s)
#pragma unroll
        for (int c = 0; c < 4; ++c) Oc[s][c] = (f32x4){0.f, 0.f, 0.f, 0.f};
    f32x4 Lc[2];
#pragma unroll
    for (int s = 0; s < 2; ++s) Lc[s] = (f32x4){0.f, 0.f, 0.f, 0.f};
    const short ob = (short)0x3F80;                         // bf16 1.0
    const bf16x8 onesf = {ob, ob, ob, ob, ob, ob, ob, ob};

    // prologue: stage tiles 0,1,2 (6 loads in flight)
#pragma unroll
    for (int pt = 0; pt < 3; ++pt) {
        ushort* db = SG + pt * 4096;
        gload_lds16(kb + (size_t)(pt * 32) * DHD + ksrc, db + kdst);
        gload_lds16(vb + pt * 32 + vsrc, db + 2048 + vdst);
    }

    for (int t = 0; t < 32; ++t) {
        // retire OWN tile-t loads; tiles t+1,t+2 stay in flight across barrier
        if (t < 30)       asm volatile("s_waitcnt vmcnt(4)" ::: "memory");
        else if (t == 30) asm volatile("s_waitcnt vmcnt(2)" ::: "memory");
        else              asm volatile("s_waitcnt vmcnt(0)" ::: "memory");
        __builtin_amdgcn_s_barrier();

        if (t + 3 < 32) {   // stage tile t+3 into buf freed at t-1
            ushort* db = SG + ((t + 3) & 3) * 4096;
            gload_lds16(kb + (size_t)((t + 3) * 32) * DHD + ksrc, db + kdst);
            gload_lds16(vb + (t + 3) * 32 + vsrc, db + 2048 + vdst);
        }
        const ushort* buf = SG + (t & 3) * 4096;

        bf16x8 kf[2][2], vf[4];
#pragma unroll
        for (int m = 0; m < 2; ++m)
#pragma unroll
            for (int hh = 0; hh < 2; ++hh)
                kf[m][hh] = *(const bf16x8*)(buf + koff[m][hh]);
#pragma unroll
        for (int c = 0; c < 4; ++c)
            vf[c] = *(const bf16x8*)(buf + voff[c]);

#pragma unroll
        for (int s = 0; s < 2; ++s) {
            f32x4 s0 = (f32x4){0.f, 0.f, 0.f, 0.f};
            f32x4 s1 = (f32x4){0.f, 0.f, 0.f, 0.f};
            __builtin_amdgcn_s_setprio(1);
            s0 = __builtin_amdgcn_mfma_f32_16x16x32_bf16(kf[0][0], qf[s][0], s0, 0, 0, 0);
            s0 = __builtin_amdgcn_mfma_f32_16x16x32_bf16(kf[0][1], qf[s][1], s0, 0, 0, 0);
            s1 = __builtin_amdgcn_mfma_f32_16x16x32_bf16(kf[1][0], qf[s][0], s1, 0, 0, 0);
            s1 = __builtin_amdgcn_mfma_f32_16x16x32_bf16(kf[1][1], qf[s][1], s1, 0, 0, 0);
            __builtin_amdgcn_s_setprio(0);
            // s includes log2(e) (folded into q): p = exp2(s)

            float p0[4], p1[4];
#pragma unroll
            for (int r = 0; r < 4; ++r) {
                p0[r] = fast_exp2(s0[r]);
                p1[r] = fast_exp2(s1[r]);
            }

            union { bf16x8 v8; unsigned d[4]; } P;
            P.d[0] = pack_bf_trunc(p0[0], p0[1]);
            P.d[1] = pack_bf_trunc(p0[2], p0[3]);
            P.d[2] = pack_bf_trunc(p1[0], p1[1]);
            P.d[3] = pack_bf_trunc(p1[2], p1[3]);
            __builtin_amdgcn_s_setprio(1);
            // row-sum on the matrix pipe: every output reg = sum_k P[k][q]
            Lc[s] = __builtin_amdgcn_mfma_f32_16x16x32_bf16(onesf, P.v8, Lc[s], 0, 0, 0);
#pragma unroll
            for (int c = 0; c < 4; ++c)
                Oc[s][c] = __builtin_amdgcn_mfma_f32_16x16x32_bf16(vf[c], P.v8, Oc[s][c], 0, 0, 0);
            __builtin_amdgcn_s_setprio(0);
        }
    }

    // combine the two key-halves in LDS (reuse staging memory).
    __syncthreads();
    float* exch = (float*)SL;                 // [128 q][68 pad] f32 = 34816 B
    float* lx   = ((float*)SL) + 128 * 68;    // 128 f32
    if (grp == 1) {
#pragma unroll
        for (int s = 0; s < 2; ++s) {
            const int lq = wq * 32 + 16 * s + l16;
#pragma unroll
            for (int c = 0; c < 4; ++c)
                *(f32x4*)&exch[lq * 68 + 16 * c + 4 * quad] = Oc[s][c];
            if (quad == 0) lx[lq] = Lc[s][0];
        }
    }
    __syncthreads();
    if (grp == 0) {
        const int b = bh >> 2, h = bh & 3;
#pragma unroll
        for (int s = 0; s < 2; ++s) {
            const int lq = wq * 32 + 16 * s + l16;
            const float linv = 1.0f / (Lc[s][0] + lx[lq]);
            ushort* dst = out + (size_t)(b * NSEQ + qx * 128 + lq) * HID + h * DHD;
#pragma unroll
            for (int c = 0; c < 4; ++c) {
                const f32x4 o1 = *(const f32x4*)&exch[lq * 68 + 16 * c + 4 * quad];
                u16x4 w;
#pragma unroll
                for (int r = 0; r < 4; ++r) w[r] = f2bf((Oc[s][c][r] + o1[r]) * linv);
                *(u16x4*)(dst + 16 * c + quad * 4) = w;
            }
        }
    }
}

// ---------------------------------------------------------------------------
// Kernel 4: out_proj + bias + residual + LayerNorm (unchanged from r8).
// ---------------------------------------------------------------------------
__global__ __launch_bounds__(256) void oproj_ln_mfma(
        const ushort* __restrict__ abuf, const float* __restrict__ Qin,
        const ushort* __restrict__ WoB, const float* __restrict__ bo,
        const float* __restrict__ g, const float* __restrict__ be,
        float* __restrict__ out) {
    __shared__ float yt[16][260];
    const int wv = threadIdx.x >> 6, lane = threadIdx.x & 63;
    const int l16 = lane & 15, quad = lane >> 4;
    const int m0 = blockIdx.x * 16;
    const int n0 = wv * 64;

    f32x4 acc[4];
#pragma unroll
    for (int c = 0; c < 4; ++c) acc[c] = (f32x4){0.f, 0.f, 0.f, 0.f};

    for (int kk = 0; kk < HID; kk += 32) {
        const bf16x8 af = *(const bf16x8*)(abuf + (size_t)(m0 + l16) * HID + kk + quad * 8);
        bf16x8 bf[4];
#pragma unroll
        for (int c = 0; c < 4; ++c)
            bf[c] = *(const bf16x8*)(WoB + (size_t)(n0 + 16 * c + l16) * HID + kk + quad * 8);
#pragma unroll
        for (int c = 0; c < 4; ++c)
            acc[c] = __builtin_amdgcn_mfma_f32_16x16x32_bf16(af, bf[c], acc[c], 0, 0, 0);
    }

#pragma unroll
    for (int c = 0; c < 4; ++c) {
        const int col = n0 + 16 * c + l16;
        const float bv = bo[col];
#pragma unroll
        for (int r = 0; r < 4; ++r) {
            const int row = quad * 4 + r;
            yt[row][col] = acc[c][r] + bv + Qin[(size_t)(m0 + row) * HID + col];
        }
    }
    __syncthreads();

    float gv[4], bev[4];
#pragma unroll
    for (int u = 0; u < 4; ++u) { gv[u] = g[lane + 64 * u]; bev[u] = be[lane + 64 * u]; }

    for (int rr = 0; rr < 4; ++rr) {
        const int row = wv * 4 + rr;
        float sm = 0.f, ssq = 0.f;
        float yv[4];
#pragma unroll
        for (int u = 0; u < 4; ++u) {
            yv[u] = yt[row][lane + 64 * u];
            sm += yv[u]; ssq += yv[u] * yv[u];
        }
#pragma unroll
        for (int off = 32; off >= 1; off >>= 1) {
            sm += __shfl_xor(sm, off);
            ssq += __shfl_xor(ssq, off);
        }
        const float mu = sm * (1.f / 256.f);
        const float rs = rsqrtf(fmaxf(ssq * (1.f / 256.f) - mu * mu, 0.f) + 1e-5f);
        float* dst = out + (size_t)(m0 + row) * HID;
#pragma unroll
        for (int u = 0; u < 4; ++u)
            dst[lane + 64 * u] = (yv[u] - mu) * rs * gv[u] + bev[u];
    }
}

// ---------------------------------------------------------------------------
extern "C" void kernel_launch(void* const* d_in, const int* in_sizes, int n_in,
                              void* d_out, int out_size, void* d_ws, size_t ws_size,
                              hipStream_t stream) {
    const float* inputs       = (const float*)d_in[0];
    const float* Q_in         = (const float*)d_in[1];
    const float* input_coords = (const float*)d_in[2];
    const float* Q_in_coords  = (const float*)d_in[3];
    const float* Wq           = (const float*)d_in[4];
    const float* Wk           = (const float*)d_in[5];
    const float* Wv           = (const float*)d_in[6];
    const float* in_proj_w    = (const float*)d_in[7];
    const float* in_proj_b    = (const float*)d_in[8];
    const float* out_proj_w   = (const float*)d_in[9];
    const float* out_proj_b   = (const float*)d_in[10];
    const float* ln_g         = (const float*)d_in[11];
    const float* ln_b         = (const float*)d_in[12];
    const float* pe_w1        = (const float*)d_in[13];
    const float* pe_b1        = (const float*)d_in[14];
    const float* pe_w2        = (const float*)d_in[15];
    const float* pe_b2        = (const float*)d_in[16];

    char* ws = (char*)d_ws;
    ushort* Wb   = (ushort*)(ws);              // 768*288*2     = 442368
    ushort* WoB  = (ushort*)(ws + 442368);     // 256*256*2     = 131072
    ushort* qp   = (ushort*)(ws + 573440);     // 16384*288*2   = 9437184
    ushort* ip   = (ushort*)(ws + 10010624);   // 9437184
    ushort* qbuf = (ushort*)(ws + 19447808);   // 8388608
    ushort* kbuf = (ushort*)(ws + 27836416);   // 8388608
    ushort* vbuf = (ushort*)(ws + 36225024);   // 8388608 (transposed [bh][64][n])
    ushort* abuf = (ushort*)(ws + 44613632);   // 8388608 -> end 53002240 bytes

    prep_kernel<<<5952, 256, 0, stream>>>(input_coords, Q_in_coords,
                                          pe_w1, pe_b1, pe_w2, pe_b2,
                                          inputs, Q_in, in_proj_w,
                                          Wq, Wk, Wv, out_proj_w,
                                          ip, qp, Wb, WoB);
    qkv_mfma<<<dim3(128, 12), 256, 0, stream>>>(qp, ip, Wb, in_proj_b,
                                                qbuf, kbuf, vbuf);
    attn_kernel<<<dim3(16, 32), 512, 0, stream>>>(qbuf, kbuf, vbuf, abuf);
    oproj_ln_mfma<<<1024, 256, 0, stream>>>(abuf, Q_in, WoB, out_proj_b,
                                            ln_g, ln_b, (float*)d_out);
}